// Round 13
// baseline (837.197 us; speedup 1.0000x reference)
//
#include <hip/hip_runtime.h>
#include <math.h>

namespace {
constexpr int kB = 2;
constexpr int kM = 512;
constexpr int kN = 2048;
constexpr int kHID = 256;
constexpr int kDH = 32;
constexpr int kL = 4;
constexpr float kEPS = 1e-5f;
constexpr int kKV = 2560; // Kbig rows / Vt_big cols per batch (2048 ks + 512 qs)
}

typedef __attribute__((ext_vector_type(8))) short short8;
typedef __attribute__((ext_vector_type(4))) float f32x4;

__device__ inline ushort f2b(float f) {
  unsigned u = __builtin_bit_cast(unsigned, f);
  unsigned r = (u + 0x7fffu + ((u >> 16) & 1u)) >> 16;
  return (ushort)r;
}
__device__ inline float b2f(ushort u) {
  return __builtin_bit_cast(float, (unsigned)u << 16);
}
__device__ inline unsigned cvtpk(float lo, float hi) {
  unsigned r;
  asm("v_cvt_pk_bf16_f32 %0, %1, %2" : "=v"(r) : "v"(lo), "v"(hi));
  return r;
}
__device__ inline void gld16(ushort* lds, const ushort* g) {
  __builtin_amdgcn_global_load_lds(
      (const __attribute__((address_space(1))) void*)g,
      (__attribute__((address_space(3))) void*)lds, 16, 0, 0);
}

// dot of 8 bf16 weights with 8 f32 activations from LDS
__device__ inline float dot8(const float* a, short8 w) {
  float s = 0.f;
  #pragma unroll
  for (int jj = 0; jj < 8; ++jj) s += a[jj] * b2f((ushort)w[jj]);
  return s;
}

// ---------------- mask normalization (dtype sniffing) -> additive mask ----------------
__global__ __launch_bounds__(256) void mask_norm_kernel(
    const unsigned char* __restrict__ mraw, float* __restrict__ mf)
{
  int tid = threadIdx.x;
  __shared__ unsigned sh[4];
  if (tid < 4) sh[tid] = 0;
  __syncthreads();
  unsigned l1 = 0, l2 = 0, l3 = 0, l4 = 0;
  for (int j = 0; j < 16; ++j) {
    int p = tid * 16 + j;
    unsigned v = mraw[p];
    int r = p & 3;
    if (r == 1) l1 |= v;
    else if (r == 2) l2 |= v;
    else if (r == 3) l3 |= v;
    else if ((p & 7) == 4) l4 |= v;
  }
  if (l1) atomicOr(&sh[0], l1);
  if (l2) atomicOr(&sh[1], l2);
  if (l3) atomicOr(&sh[2], l3);
  if (l4) atomicOr(&sh[3], l4);
  __syncthreads();
  unsigned a1 = sh[0], a2 = sh[1], a3 = sh[2], a4 = sh[3];
  int mode; // 0=u8, 1=i32, 2=i64, 3=f32
  if ((a1 | a2 | a3) == 0) mode = a4 ? 1 : 2;
  else if (a1 == 0 && (a2 & ~0x80u) == 0 && (a3 & ~0x3Fu) == 0 && ((a2 | a3) != 0))
    mode = 3;
  else mode = 0;

  int i = blockIdx.x * 256 + tid;
  unsigned char v;
  if (mode == 0) v = mraw[i];
  else if (mode == 1) v = mraw[i * 4];
  else if (mode == 2) v = mraw[i * 8];
  else v = mraw[i * 4 + 3];
  mf[i] = v ? 0.f : -2.5505654e9f; // -(1e10 * scale2)
}

// ---------------- unified encoder: sinenc + add + LN1 -> bf16 ----------------
__global__ __launch_bounds__(256) void encode2_kernel(
    const float* __restrict__ qc2, const float* __restrict__ qf2,
    const float* __restrict__ qf3, const float* __restrict__ kc2,
    const float* __restrict__ kf2, const float* __restrict__ kf3,
    const float* __restrict__ g, const float* __restrict__ bb,
    ushort* __restrict__ out)
{
  int row = blockIdx.x; // 0..5119
  const float *c2d, *f2, *f3;
  int r;
  if (row < kB * kM) { c2d = qc2; f2 = qf2; f3 = qf3; r = row; }
  else { c2d = kc2; f2 = kf2; f3 = kf3; r = row - kB * kM; }
  int c = threadIdx.x;
  float coord = c2d[(size_t)r * 2 + (c >> 7)];
  int h = c & 127;
  float ex = (float)(h & ~1) * (1.0f / 128.0f);
  float inv = expf(ex * 9.210340371976184f);
  float val = coord / inv;
  float e = (h & 1) ? cosf(val) : sinf(val);
  float x = f2[(size_t)r * 256 + c] + f3[(size_t)r * 256 + c] + e;
  __shared__ float red[256];
  red[c] = x; __syncthreads();
  for (int s = 128; s > 0; s >>= 1) { if (c < s) red[c] += red[c + s]; __syncthreads(); }
  float mean = red[0] * (1.0f / 256.0f);
  __syncthreads();
  float d = x - mean;
  red[c] = d * d; __syncthreads();
  for (int s = 128; s > 0; s >>= 1) { if (c < s) red[c] += red[c + s]; __syncthreads(); }
  float var = red[0] * (1.0f / 256.0f);
  out[(size_t)row * 256 + c] = f2b(d * rsqrtf(var + kEPS) * g[c] + bb[c]);
}

// ---------------- batched weight convert + transpose ----------------
struct WJobs {
  const float* W[7]; ushort* Wt[7];
  int K[7], C[7], off[7];
};
__global__ __launch_bounds__(256) void wconv_all_kernel(WJobs J)
{
  __shared__ float t[32][33];
  int bid = blockIdx.x;
  int j = 0;
  #pragma unroll
  for (int q = 1; q < 7; ++q) if (bid >= J.off[q]) j = q;
  int tl = bid - J.off[j];
  int K = J.K[j], C = J.C[j];
  int tpl = (K >> 5) * (C >> 5);
  int layer = tl / tpl, rem = tl - layer * tpl;
  int kt = rem % (K >> 5), ct = rem / (K >> 5);
  const float* Wl = J.W[j] + (size_t)layer * K * C;
  ushort* Wtl = J.Wt[j] + (size_t)layer * K * C;
  int k0 = kt * 32, c0 = ct * 32;
  int tx = threadIdx.x & 31, ty = threadIdx.x >> 5;
  for (int i = ty; i < 32; i += 8) t[i][tx] = Wl[(size_t)(k0 + i) * C + c0 + tx];
  __syncthreads();
  for (int i = ty; i < 32; i += 8)
    Wtl[(size_t)(c0 + i) * K + k0 + tx] = f2b(t[tx][i]);
}

// ---------------- batched bf16 MFMA GEMM (64x64 tiles) ----------------
struct GDesc {
  const ushort* A; const ushort* Bt; const float* bias; const float* res; void* out;
  int R, K, C, flags;          // flags: 1 relu, 2 bf16-out, 4 transposed-Vt-out
  int in_rpb, out_rpb, out_off, vt_stride;
};
struct GBatch { GDesc d[5]; };

__global__ __launch_bounds__(256) void gemmx_kernel(GBatch bt)
{
  GDesc d = bt.d[blockIdx.z];
  int r0 = blockIdx.x * 64;
  if (r0 >= d.R) return;
  int c0 = blockIdx.y * 64;

  __shared__ ushort As[4096];
  __shared__ ushort Bs[4096];
  int tid = threadIdx.x;
  int lam = tid & 63, wv = tid >> 6;
  int wr = wv >> 1, wc = wv & 1;
  int K = d.K;
  int srow8 = lam >> 3;
  int sxor = (lam & 7) ^ srow8;

  f32x4 acc[2][2] = {};

  for (int k0 = 0; k0 < K; k0 += 64) {
    #pragma unroll
    for (int i = 0; i < 2; ++i) {
      int row = 16 * wv + 8 * i + srow8;
      gld16(As + wv * 1024 + i * 512,
            d.A + (size_t)(r0 + row) * K + k0 + 8 * sxor);
      gld16(Bs + wv * 1024 + i * 512,
            d.Bt + (size_t)(c0 + row) * K + k0 + 8 * sxor);
    }
    __syncthreads();
    #pragma unroll
    for (int ks = 0; ks < 2; ++ks) {
      short8 af[2], bf_[2];
      #pragma unroll
      for (int m = 0; m < 2; ++m) {
        int ra = wr * 32 + m * 16 + (lam & 15);
        int ch = (ks * 4 + (lam >> 4)) ^ (ra & 7);
        af[m] = *(const short8*)(As + ra * 64 + ch * 8);
      }
      #pragma unroll
      for (int n = 0; n < 2; ++n) {
        int rb = wc * 32 + n * 16 + (lam & 15);
        int ch = (ks * 4 + (lam >> 4)) ^ (rb & 7);
        bf_[n] = *(const short8*)(Bs + rb * 64 + ch * 8);
      }
      #pragma unroll
      for (int m = 0; m < 2; ++m)
        #pragma unroll
        for (int n = 0; n < 2; ++n)
          acc[m][n] = __builtin_amdgcn_mfma_f32_16x16x32_bf16(
              af[m], bf_[n], acc[m][n], 0, 0, 0);
    }
    __syncthreads();
  }

  if (!(d.flags & 4)) {
    #pragma unroll
    for (int m = 0; m < 2; ++m) {
      #pragma unroll
      for (int reg = 0; reg < 4; ++reg) {
        int gr = r0 + wr * 32 + m * 16 + (lam >> 4) * 4 + reg;
        int bidx = gr / d.in_rpb, rr = gr - bidx * d.in_rpb;
        size_t orow = (size_t)bidx * d.out_rpb + d.out_off + rr;
        #pragma unroll
        for (int n = 0; n < 2; ++n) {
          int gc = c0 + wc * 32 + n * 16 + (lam & 15);
          float v = acc[m][n][reg] + d.bias[gc];
          if (d.res) v += d.res[(size_t)gr * d.C + gc];
          if (d.flags & 1) v = fmaxf(v, 0.f);
          if (d.flags & 2) ((ushort*)d.out)[orow * d.C + gc] = f2b(v);
          else ((float*)d.out)[orow * d.C + gc] = v;
        }
      }
    }
  } else {
    #pragma unroll
    for (int m = 0; m < 2; ++m)
      #pragma unroll
      for (int n = 0; n < 2; ++n)
        #pragma unroll
        for (int reg = 0; reg < 4; ++reg) {
          int col = wc * 32 + n * 16 + (lam & 15);
          int row = wr * 32 + m * 16 + (lam >> 4) * 4 + reg;
          float v = acc[m][n][reg] + d.bias[c0 + col];
          As[col * 64 + (((row >> 3) ^ (col & 7)) << 3) + (row & 7)] = f2b(v);
        }
    __syncthreads();
    int col2 = tid >> 2, rc = tid & 3;
    #pragma unroll
    for (int u = 0; u < 2; ++u) {
      int rowc = rc * 2 + u;
      short8 val = *(const short8*)(As + col2 * 64 + ((rowc ^ (col2 & 7)) << 3));
      int r = r0 + rowc * 8;
      int bidx = r / d.in_rpb, rr = r - bidx * d.in_rpb;
      *(short8*)((ushort*)d.out +
                 ((size_t)bidx * 256 + c0 + col2) * d.vt_stride + d.out_off + rr) = val;
    }
  }
}

// ---------------- fused GEMM + bias (+res) + LayerNorm: 16-row x 256-col blocks ----------------
__global__ __launch_bounds__(256) void gemmln_kernel(
    const ushort* __restrict__ A, const ushort* __restrict__ Bt,
    const float* __restrict__ bias, const float* __restrict__ res,
    const float* __restrict__ g, const float* __restrict__ bb,
    float* __restrict__ outf, ushort* __restrict__ outb, int R, int K)
{
  __shared__ ushort As[16 * 64];
  __shared__ ushort Bs[256 * 64];
  __shared__ float redL[16][4];
  int r0 = blockIdx.x * 16;
  int tid = threadIdx.x;
  int lam = tid & 63, wv = tid >> 6;
  int srow8 = lam >> 3;
  int sxor = (lam & 7) ^ srow8;

  f32x4 acc[4] = {};

  for (int k0 = 0; k0 < K; k0 += 64) {
    if (wv < 2)
      gld16(As + wv * 512, A + (size_t)(r0 + wv * 8 + srow8) * K + k0 + 8 * sxor);
    #pragma unroll
    for (int j = 0; j < 8; ++j) {
      int cc = wv * 8 + j;
      gld16(Bs + cc * 512, Bt + (size_t)(cc * 8 + srow8) * K + k0 + 8 * sxor);
    }
    __syncthreads();
    #pragma unroll
    for (int ks = 0; ks < 2; ++ks) {
      int ra = lam & 15;
      int cha = (ks * 4 + (lam >> 4)) ^ (ra & 7);
      short8 af = *(const short8*)(As + ra * 64 + cha * 8);
      #pragma unroll
      for (int cg = 0; cg < 4; ++cg) {
        int rb = wv * 64 + cg * 16 + (lam & 15);
        int chb = (ks * 4 + (lam >> 4)) ^ (rb & 7);
        short8 bf_ = *(const short8*)(Bs + rb * 64 + chb * 8);
        acc[cg] = __builtin_amdgcn_mfma_f32_16x16x32_bf16(af, bf_, acc[cg], 0, 0, 0);
      }
    }
    __syncthreads();
  }

  int col_lo = lam & 15, rsel = lam >> 4;
  float v[4][4];
  #pragma unroll
  for (int cg = 0; cg < 4; ++cg) {
    int col = wv * 64 + cg * 16 + col_lo;
    float bi = bias[col];
    #pragma unroll
    for (int reg = 0; reg < 4; ++reg) {
      int row = r0 + rsel * 4 + reg;
      float x = acc[cg][reg] + bi;
      if (res) x += res[(size_t)row * 256 + col];
      v[cg][reg] = x;
    }
  }
  float mean[4];
  {
    float ps[4];
    #pragma unroll
    for (int reg = 0; reg < 4; ++reg) {
      ps[reg] = v[0][reg] + v[1][reg] + v[2][reg] + v[3][reg];
      #pragma unroll
      for (int o = 1; o < 16; o <<= 1) ps[reg] += __shfl_xor(ps[reg], o);
    }
    if (col_lo == 0)
      #pragma unroll
      for (int reg = 0; reg < 4; ++reg) redL[rsel * 4 + reg][wv] = ps[reg];
    __syncthreads();
    #pragma unroll
    for (int reg = 0; reg < 4; ++reg) {
      int rr = rsel * 4 + reg;
      mean[reg] = (redL[rr][0] + redL[rr][1] + redL[rr][2] + redL[rr][3]) * (1.0f / 256.0f);
    }
    __syncthreads();
  }
  float rs_[4];
  {
    float ps[4];
    #pragma unroll
    for (int reg = 0; reg < 4; ++reg) {
      float s = 0.f;
      #pragma unroll
      for (int cg = 0; cg < 4; ++cg) {
        float dd = v[cg][reg] - mean[reg];
        s += dd * dd;
      }
      ps[reg] = s;
      #pragma unroll
      for (int o = 1; o < 16; o <<= 1) ps[reg] += __shfl_xor(ps[reg], o);
    }
    if (col_lo == 0)
      #pragma unroll
      for (int reg = 0; reg < 4; ++reg) redL[rsel * 4 + reg][wv] = ps[reg];
    __syncthreads();
    #pragma unroll
    for (int reg = 0; reg < 4; ++reg) {
      int rr = rsel * 4 + reg;
      float var = (redL[rr][0] + redL[rr][1] + redL[rr][2] + redL[rr][3]) * (1.0f / 256.0f);
      rs_[reg] = rsqrtf(var + kEPS);
    }
  }
  #pragma unroll
  for (int cg = 0; cg < 4; ++cg) {
    int col = wv * 64 + cg * 16 + col_lo;
    float gg = g[col], bv = bb[col];
    #pragma unroll
    for (int reg = 0; reg < 4; ++reg) {
      int row = r0 + rsel * 4 + reg;
      float y = (v[cg][reg] - mean[reg]) * rs_[reg] * gg + bv;
      outf[(size_t)row * 256 + col] = y;
      outb[(size_t)row * 256 + col] = f2b(y);
    }
  }
}

// ---------------- MFMA flash attention v6b: LDS K/V^T with bank-spread padded rows ----------------
// KsL rows 40 ushorts (80B): bank-group = 5*key+chunk spread; VtL rows 80 ushorts (160B).
__global__ __launch_bounds__(256) void attn6_kernel(
    const ushort* __restrict__ Qp, const ushort* __restrict__ Kp,
    const ushort* __restrict__ Vt, float* __restrict__ Pp,
    const float* __restrict__ madd,
    int Sq, int k_rpb, int vt_stride, int self_off, int slen, int ns)
{
  __shared__ ushort KsL[64 * 40];  // [key][chunk^((key>>1)&3)], padded stride 80B
  __shared__ ushort VtL[32 * 80];  // [d][chunk^(d&7)], padded stride 160B
  int bh = blockIdx.x;
  int b = bh >> 3, h = bh & 7;
  int sidx = blockIdx.z;
  int tid = threadIdx.x;
  int lane = tid & 63;
  int qlane = lane & 15, g = lane >> 4;
  int gq = blockIdx.y * 64 + (tid >> 6) * 16 + qlane;
  const float scale2 = 0.17677669529663688f * 1.4426950408889634f;

  short8 qB = *(const short8*)(Qp + ((size_t)(b * Sq + gq)) * 256 + h * 32 + g * 8);

  float mi = -3.0e38f, li = 0.f;
  f32x4 acc0 = {}, acc1 = {};

  if (self_off >= 0 && sidx == 0) {
    const ushort* kr = Kp + ((size_t)(b * k_rpb + self_off + gq)) * 256 + h * 32 + g * 8;
    short8 k8 = *(const short8*)kr;
    float part = 0.f;
    #pragma unroll
    for (int j = 0; j < 8; ++j) part += b2f((ushort)qB[j]) * b2f((ushort)k8[j]);
    part += __shfl_xor(part, 16);
    part += __shfl_xor(part, 32);
    mi = part * scale2;
    li = 1.f;
    const ushort* vb = Vt + ((size_t)(b * 256 + h * 32)) * vt_stride + self_off + gq;
    #pragma unroll
    for (int r = 0; r < 4; ++r) {
      acc0[r] = b2f(vb[(size_t)(4 * g + r) * vt_stride]);
      acc1[r] = b2f(vb[(size_t)(16 + 4 * g + r) * vt_stride]);
    }
  }

  const float* mb = madd + (size_t)b * kN;
  int skey = tid >> 2, sc = tid & 3;   // K staging: key row, 8-elem chunk
  int sd = tid >> 3, sc8 = tid & 7;    // V^T staging: d row, 8-key chunk
  const ushort* Ksrc = Kp + ((size_t)(b * k_rpb + skey)) * 256 + h * 32 + sc * 8;
  const ushort* Vsrc = Vt + ((size_t)(b * 256 + h * 32 + sd)) * vt_stride + sc8 * 8;
  ushort* Kdst = KsL + skey * 40 + ((sc ^ ((skey >> 1) & 3)) << 3);
  ushort* Vdst = VtL + sd * 80 + ((sc8 ^ (sd & 7)) << 3);

  int base = sidx * slen;
  int ntile = slen >> 6;

  for (int it = 0; it < ntile; ++it) {
    int n0 = base + it * 64;
    __syncthreads();  // prev tile's LDS reads complete
    *(short8*)Kdst = *(const short8*)(Ksrc + (size_t)n0 * 256);
    *(short8*)Vdst = *(const short8*)(Vsrc + n0);
    __syncthreads();

    float4 m4[4];
    #pragma unroll
    for (int f = 0; f < 4; ++f)
      m4[f] = *(const float4*)(mb + n0 + 16 * f + 4 * g);

    f32x4 st[4];
    __builtin_amdgcn_s_setprio(1);
    #pragma unroll
    for (int f = 0; f < 4; ++f) {
      int key = f * 16 + qlane;
      short8 kf = *(const short8*)(KsL + key * 40 + ((g ^ ((key >> 1) & 3)) << 3));
      st[f] = __builtin_amdgcn_mfma_f32_16x16x32_bf16(
          kf, qB, (f32x4){0.f, 0.f, 0.f, 0.f}, 0, 0, 0);
    }
    __builtin_amdgcn_s_setprio(0);

    float p[4][4];
    float tm = -3.0e38f;
    #pragma unroll
    for (int f = 0; f < 4; ++f) {
      float mm[4] = {m4[f].x, m4[f].y, m4[f].z, m4[f].w};
      #pragma unroll
      for (int r = 0; r < 4; ++r) {
        float s = fmaf(st[f][r], scale2, mm[r]);
        p[f][r] = s;
        tm = fmaxf(tm, s);
      }
    }
    tm = fmaxf(tm, __shfl_xor(tm, 16));
    tm = fmaxf(tm, __shfl_xor(tm, 32));
    if (__any(tm > mi + 11.5f)) {  // defer-max
      float nm = fmaxf(mi, tm);
      float fs = exp2f(mi - nm);
      li *= fs; mi = nm;
      #pragma unroll
      for (int r = 0; r < 4; ++r) { acc0[r] *= fs; acc1[r] *= fs; }
    }
    float ls = 0.f;
    #pragma unroll
    for (int f = 0; f < 4; ++f)
      #pragma unroll
      for (int r = 0; r < 4; ++r) {
        float pv = exp2f(p[f][r] - mi);
        p[f][r] = pv;
        ls += pv;
      }
    ls += __shfl_xor(ls, 16);
    ls += __shfl_xor(ls, 32);
    li += ls;

    // P^T -> bf16 B-fragments via pack + 8 shfl per 32-key half
    unsigned pkw[4][2];
    #pragma unroll
    for (int f = 0; f < 4; ++f) {
      pkw[f][0] = cvtpk(p[f][0], p[f][1]);
      pkw[f][1] = cvtpk(p[f][2], p[f][3]);
    }
    int src0 = qlane | ((2 * (g & 1)) << 4);
    int src1 = src0 + 16;
    bool hi = g >= 2;
    #pragma unroll
    for (int t = 0; t < 2; ++t) {
      unsigned t0 = (unsigned)__shfl((int)pkw[2 * t][0], src0);
      unsigned t1 = (unsigned)__shfl((int)pkw[2 * t][1], src0);
      unsigned t2 = (unsigned)__shfl((int)pkw[2 * t][0], src1);
      unsigned t3 = (unsigned)__shfl((int)pkw[2 * t][1], src1);
      unsigned u0 = (unsigned)__shfl((int)pkw[2 * t + 1][0], src0);
      unsigned u1 = (unsigned)__shfl((int)pkw[2 * t + 1][1], src0);
      unsigned u2 = (unsigned)__shfl((int)pkw[2 * t + 1][0], src1);
      unsigned u3 = (unsigned)__shfl((int)pkw[2 * t + 1][1], src1);
      union { unsigned u[4]; short8 v; } pb;
      pb.u[0] = hi ? u0 : t0;
      pb.u[1] = hi ? u1 : t1;
      pb.u[2] = hi ? u2 : t2;
      pb.u[3] = hi ? u3 : t3;
      __builtin_amdgcn_s_setprio(1);
      int d0 = qlane, d1 = 16 + qlane;
      short8 vf0 = *(const short8*)(VtL + d0 * 80 + (((t * 4 + g) ^ (d0 & 7)) << 3));
      acc0 = __builtin_amdgcn_mfma_f32_16x16x32_bf16(vf0, pb.v, acc0, 0, 0, 0);
      short8 vf1 = *(const short8*)(VtL + d1 * 80 + (((t * 4 + g) ^ (d1 & 7)) << 3));
      acc1 = __builtin_amdgcn_mfma_f32_16x16x32_bf16(vf1, pb.v, acc1, 0, 0, 0);
      __builtin_amdgcn_s_setprio(0);
    }
  }

  float* rec = Pp + ((size_t)(bh * Sq + gq) * ns + sidx) * 20;
  if (g == 0) { rec[0] = mi; rec[1] = li; }
  ushort* accp = (ushort*)(rec + 2);
  uint2 w0, w1;
  w0.x = cvtpk(acc0[0], acc0[1]); w0.y = cvtpk(acc0[2], acc0[3]);
  w1.x = cvtpk(acc1[0], acc1[1]); w1.y = cvtpk(acc1[2], acc1[3]);
  *(uint2*)(accp + 4 * g) = w0;
  *(uint2*)(accp + 16 + 4 * g) = w1;
}

// ---------------- split-K combine: merge ns partials, write bf16 AO ----------------
__global__ __launch_bounds__(256) void combine_kernel(
    const float* __restrict__ Pp, ushort* __restrict__ AO, int Sq, int ns)
{
  int r = blockIdx.x * 8 + (threadIdx.x >> 5);
  int d = threadIdx.x & 31;
  int bh = r / Sq, q = r - bh * Sq;
  int b = bh >> 3, h = bh & 7;
  const float* rb = Pp + (size_t)r * ns * 20;
  float M = -3.0e38f;
  for (int s2 = 0; s2 < ns; ++s2) M = fmaxf(M, rb[s2 * 20]);
  float L = 0.f, O = 0.f;
  for (int s2 = 0; s2 < ns; ++s2) {
    float w = exp2f(rb[s2 * 20] - M);
    L += rb[s2 * 20 + 1] * w;
    O += w * b2f(((const ushort*)(rb + s2 * 20 + 2))[d]);
  }
  AO[((size_t)(b * Sq + q)) * 256 + h * 32 + d] = f2b(O / L);
}

// ---------------- fused cls attention (one block per (b,h)) ----------------
__global__ __launch_bounds__(256) void cls_attn_kernel(
    const float* __restrict__ cls_s,
    const ushort* __restrict__ WqT, const float* __restrict__ bq,
    const ushort* __restrict__ WkT, const float* __restrict__ bk,
    const ushort* __restrict__ WvT, const float* __restrict__ bv,
    const ushort* __restrict__ Kbig, const ushort* __restrict__ Vt,
    float* __restrict__ AOc)
{
  __shared__ float c0f[256], qv[32], k0v[32], v0v[32];
  __shared__ float red[256];
  __shared__ float sarr[2560];
  __shared__ float scl[4];
  const float scale2 = 0.17677669529663688f * 1.4426950408889634f;
  int b = blockIdx.x >> 3, h = blockIdx.x & 7;
  int t = threadIdx.x;
  c0f[t] = cls_s[b * 256 + t];
  __syncthreads();

  const ushort* Wm[3] = {WqT, WkT, WvT};
  const float* Bi[3] = {bq, bk, bv};
  float* Ov[3] = {qv, k0v, v0v};
  for (int pi = 0; pi < 3; ++pi) {
    int d = t >> 3, sl = t & 7;
    const ushort* wrow = Wm[pi] + (size_t)(h * 32 + d) * 256 + sl * 32;
    float part = 0.f;
    #pragma unroll
    for (int j = 0; j < 32; j += 8) {
      short8 w8 = *(const short8*)(wrow + j);
      #pragma unroll
      for (int jj = 0; jj < 8; ++jj) part += c0f[sl * 32 + j + jj] * b2f((ushort)w8[jj]);
    }
    red[t] = part;
    __syncthreads();
    if (t < 32) {
      float sum = 0.f;
      #pragma unroll
      for (int s = 0; s < 8; ++s) sum += red[t * 8 + s];
      Ov[pi][t] = sum + Bi[pi][h * 32 + t];
    }
    __syncthreads();
  }

  if (t < 32) red[t] = qv[t] * k0v[t];
  __syncthreads();
  if (t == 0) {
    float sc = 0.f;
    for (int j = 0; j < 32; ++j) sc += red[j];
    scl[0] = sc * scale2;
  }
  __syncthreads();

  float lmax = -3.0e38f;
  for (int it = 0; it < 10; ++it) {
    int key = t + it * 256;
    const ushort* krow = Kbig + ((size_t)(b * kKV + key)) * 256 + h * 32;
    float sdot = 0.f;
    #pragma unroll
    for (int j = 0; j < 4; ++j) {
      short8 k8 = ((const short8*)krow)[j];
      #pragma unroll
      for (int jj = 0; jj < 8; ++jj) sdot += qv[j * 8 + jj] * b2f((ushort)k8[jj]);
    }
    sdot *= scale2;
    sarr[key] = sdot;
    lmax = fmaxf(lmax, sdot);
  }
  red[t] = lmax;
  __syncthreads();
  for (int s = 128; s > 0; s >>= 1) { if (t < s) red[t] = fmaxf(red[t], red[t + s]); __syncthreads(); }
  if (t == 0) scl[1] = fmaxf(red[0], scl[0]);
  __syncthreads();
  float M = scl[1];
  float lsum = 0.f;
  for (int it = 0; it < 10; ++it) {
    int key = t + it * 256;
    float pv = exp2f(sarr[key] - M);
    sarr[key] = pv;
    lsum += pv;
  }
  red[t] = lsum;
  __syncthreads();
  for (int s = 128; s > 0; s >>= 1) { if (t < s) red[t] += red[t + s]; __syncthreads(); }
  if (t == 0) {
    scl[3] = exp2f(scl[0] - M);
    scl[2] = red[0] + scl[3];
  }
  __syncthreads();

  {
    int d = t & 31, sl = t >> 5;
    const ushort* vrow = Vt + ((size_t)(b * 256 + h * 32 + d)) * kKV + sl * 320;
    float acc = 0.f;
    for (int j = 0; j < 320; j += 8) {
      short8 v8 = *(const short8*)(vrow + j);
      #pragma unroll
      for (int jj = 0; jj < 8; ++jj) acc += sarr[sl * 320 + j + jj] * b2f((ushort)v8[jj]);
    }
    red[sl * 32 + d] = acc;
  }
  __syncthreads();
  if (t < 32) {
    float o = scl[3] * v0v[t];
    #pragma unroll
    for (int s = 0; s < 8; ++s) o += red[s * 32 + t];
    AOc[b * 256 + h * 32 + t] = o / scl[2];
  }
}

// ---------------- fused cls MLP (1024 threads, 8-lane-per-row coalesced reads) ----------------
__device__ inline float blk_sum1024(float v, float* red, int t) {
  red[t] = v; __syncthreads();
  for (int s = 512; s > 0; s >>= 1) {
    if (t < s) red[t] += red[t + s];
    __syncthreads();
  }
  float r = red[0];
  __syncthreads();
  return r;
}

__global__ __launch_bounds__(1024) void cls_mlp_kernel(
    const float* __restrict__ AOc, float* __restrict__ cls_s,
    const ushort* __restrict__ WdT, const float* __restrict__ bd,
    const float* __restrict__ ag, const float* __restrict__ ab,
    const ushort* __restrict__ W1T, const float* __restrict__ b1,
    const ushort* __restrict__ W2T, const float* __restrict__ b2,
    const float* __restrict__ fg, const float* __restrict__ fb)
{
  __shared__ float oL[256], r0L[256], aL[256], ffL[1024], vL[256], red[1024];
  int b = blockIdx.x, t = threadIdx.x; // 0..1023
  if (t < 256) { oL[t] = AOc[b * 256 + t]; r0L[t] = cls_s[b * 256 + t]; }
  __syncthreads();

  int r8 = t >> 3, c8 = t & 7; // 8 lanes cooperate on one row (coalesced 128B/row)
  // Wd projection (256 rows, K=256): 2 passes of 128 rows
  #pragma unroll
  for (int p = 0; p < 2; ++p) {
    int row = p * 128 + r8;
    const ushort* wr_ = WdT + (size_t)row * 256 + c8 * 8;
    float a0 = 0.f, a1 = 0.f, a2 = 0.f, a3 = 0.f;
    a0 = dot8(oL + c8 * 8, *(const short8*)(wr_));
    a1 = dot8(oL + c8 * 8 + 64, *(const short8*)(wr_ + 64));
    a2 = dot8(oL + c8 * 8 + 128, *(const short8*)(wr_ + 128));
    a3 = dot8(oL + c8 * 8 + 192, *(const short8*)(wr_ + 192));
    float s = (a0 + a1) + (a2 + a3);
    s += __shfl_xor(s, 1);
    s += __shfl_xor(s, 2);
    s += __shfl_xor(s, 4);
    if (c8 == 0) vL[row] = s + bd[row] + r0L[row];
  }
  __syncthreads();
  // LN #1
  {
    float x = (t < 256) ? vL[t] : 0.f;
    float mean = blk_sum1024(x, red, t) * (1.0f / 256.0f);
    float d = (t < 256) ? (vL[t] - mean) : 0.f;
    float var = blk_sum1024(d * d, red, t) * (1.0f / 256.0f);
    float rs = rsqrtf(var + kEPS);
    if (t < 256) aL[t] = d * rs * ag[t] + ab[t];
  }
  __syncthreads();
  // FF1 (1024 rows, K=256) + relu: 8 passes of 128 rows
  #pragma unroll
  for (int p = 0; p < 8; ++p) {
    int row = p * 128 + r8;
    const ushort* w1r = W1T + (size_t)row * 256 + c8 * 8;
    float a0 = dot8(aL + c8 * 8, *(const short8*)(w1r));
    float a1 = dot8(aL + c8 * 8 + 64, *(const short8*)(w1r + 64));
    float a2 = dot8(aL + c8 * 8 + 128, *(const short8*)(w1r + 128));
    float a3 = dot8(aL + c8 * 8 + 192, *(const short8*)(w1r + 192));
    float s = (a0 + a1) + (a2 + a3);
    s += __shfl_xor(s, 1);
    s += __shfl_xor(s, 2);
    s += __shfl_xor(s, 4);
    if (c8 == 0) ffL[row] = fmaxf(s + b1[row], 0.f);
  }
  __syncthreads();
  // FF2 (256 rows, K=1024): 2 passes of 128 rows; 16 chunks per thread
  #pragma unroll
  for (int p = 0; p < 2; ++p) {
    int row = p * 128 + r8;
    const ushort* w2r = W2T + (size_t)row * 1024 + c8 * 8;
    float a0 = 0.f, a1 = 0.f, a2 = 0.f, a3 = 0.f;
    #pragma unroll
    for (int j = 0; j < 1024; j += 256) {
      a0 += dot8(ffL + c8 * 8 + j, *(const short8*)(w2r + j));
      a1 += dot8(ffL + c8 * 8 + j + 64, *(const short8*)(w2r + j + 64));
      a2 += dot8(ffL + c8 * 8 + j + 128, *(const short8*)(w2r + j + 128));
      a3 += dot8(ffL + c8 * 8 + j + 192, *(const short8*)(w2r + j + 192));
    }
    float s = (a0 + a1) + (a2 + a3);
    s += __shfl_xor(s, 1);
    s += __shfl_xor(s, 2);
    s += __shfl_xor(s, 4);
    if (c8 == 0) vL[row] = s + b2[row] + aL[row];
  }
  __syncthreads();
  // LN #2
  {
    float x = (t < 256) ? vL[t] : 0.f;
    float mean = blk_sum1024(x, red, t) * (1.0f / 256.0f);
    float d = (t < 256) ? (vL[t] - mean) : 0.f;
    float var = blk_sum1024(d * d, red, t) * (1.0f / 256.0f);
    float rs = rsqrtf(var + kEPS);
    if (t < 256) cls_s[b * 256 + t] = d * rs * fg[t] + fb[t];
  }
}

__global__ void cls_init_kernel(const float* __restrict__ cf, float* __restrict__ cls)
{
  int i = blockIdx.x * 256 + threadIdx.x;
  cls[i] = cf[i & 255];
}

__global__ __launch_bounds__(256) void copyout_kernel(
    const float* __restrict__ qs, const float* __restrict__ ks,
    const float* __restrict__ cls, float* __restrict__ out)
{
  int i = blockIdx.x * 256 + threadIdx.x;
  float v;
  if (i < 262144) v = qs[i];
  else if (i < 1310720) v = ks[i - 262144];
  else v = cls[i - 1310720];
  out[i] = v;
}

extern "C" void kernel_launch(void* const* d_in, const int* in_sizes, int n_in,
                              void* d_out, int out_size, void* d_ws, size_t ws_size,
                              hipStream_t stream)
{
  const float* qc2    = (const float*)d_in[0];
  const float* qf2    = (const float*)d_in[1];
  const float* qf3    = (const float*)d_in[2];
  const float* kc2    = (const float*)d_in[3];
  const float* kf2    = (const float*)d_in[4];
  const float* kf3    = (const float*)d_in[5];
  const unsigned char* mraw = (const unsigned char*)d_in[6];
  const float* ln1_g  = (const float*)d_in[7];
  const float* ln1_b  = (const float*)d_in[8];
  const float* dc_W   = (const float*)d_in[9];
  const float* dc_b   = (const float*)d_in[10];
  const float* dcln_g = (const float*)d_in[11];
  const float* dcln_b = (const float*)d_in[12];
  const float* cls_f  = (const float*)d_in[13];
  const float* Wq     = (const float*)d_in[14];
  const float* bq     = (const float*)d_in[15];
  const float* Wk     = (const float*)d_in[16];
  const float* bk     = (const float*)d_in[17];
  const float* Wv     = (const float*)d_in[18];
  const float* bv     = (const float*)d_in[19];
  const float* Wd     = (const float*)d_in[20];
  const float* bd     = (const float*)d_in[21];
  const float* aln_g  = (const float*)d_in[22];
  const float* aln_b  = (const float*)d_in[23];
  const float* W1     = (const float*)d_in[24];
  const float* b1     = (const float*)d_in[25];
  const float* W2     = (const float*)d_in[26];
  const float* b2     = (const float*)d_in[27];
  const float* fln_g  = (const float*)d_in[28];
  const float* fln_b  = (const float*)d_in[29];

  float* ws = (float*)d_ws;
  float* maskf = ws + 0;          // 4096 (additive)
  float* qs_s  = ws + 4096;       // 262144   (qs_s and ks_s adjacent!)
  float* ks_s  = ws + 266240;     // 1048576
  float* cls_s = ws + 1314816;    // 512
  float* AOc   = ws + 1315328;    // 512
  float* Scr   = ws + 1316864;
  float* Ta    = Scr;                 // 1048576 ('a' f32)
  float* ksPart = Scr + 1048576;      // ns=2: 16*2048*2*20 = 1310720
  float* qsPart = Scr + 1048576;      // ns=4: 16*512*4*20 = 655360 (reuses region)
  ushort* ub   = (ushort*)(ws + 4986880);
  ushort* qs_b   = ub + 0;            // 262144  (qs_b and ks_b adjacent!)
  ushort* ks_b   = ub + 262144;       // 1048576
  ushort* T2b    = ub + 1310720;      // 1048576 ('a' bf16)
  ushort* Kbig   = ub + 2359296;      // 1310720 (B x 2560 x 256)
  ushort* Vt_ks  = ub + 3670016;      // 1048576 (B x 256 x 2048)
  ushort* Vt_big = ub + 4718592;      // 1310720 (B x 256 x 2560)
  ushort* FFb    = ub + 6029312;      // 4194304 (overlays encT|Qb|Kks|AOb)
  ushort* encT   = FFb + 0;           // 1310720 (5120 x 256)
  ushort* Qb     = FFb + 0;           // 1048576
  ushort* Kks    = FFb + 1048576;     // 1048576
  ushort* AOb    = FFb + 2097152;     // 1048576
  ushort* wts    = ub + 10223616;
  ushort* dcWt = wts;
  ushort* WqT  = wts + 65536;
  ushort* WkT  = WqT + 262144;
  ushort* WvT  = WkT + 262144;
  ushort* WdT  = WvT + 262144;
  ushort* W1T  = WdT + 262144;
  ushort* W2T  = W1T + 1048576;
  // total ~44.7 MB

  auto mk = [](const ushort* A, const ushort* Bt, const float* bias, const float* res,
               void* out, int R, int K, int C, int flags,
               int in_rpb, int out_rpb, int out_off, int vt_stride) {
    GDesc g; g.A = A; g.Bt = Bt; g.bias = bias; g.res = res; g.out = out;
    g.R = R; g.K = K; g.C = C; g.flags = flags; g.in_rpb = in_rpb;
    g.out_rpb = out_rpb; g.out_off = out_off; g.vt_stride = vt_stride; return g;
  };
  auto launch = [&](const GDesc* ds, int n) {
    GBatch bt{};
    int maxR = 0;
    for (int i = 0; i < n; ++i) { bt.d[i] = ds[i]; if (ds[i].R > maxR) maxR = ds[i].R; }
    gemmx_kernel<<<dim3(maxR / 64, ds[0].C / 64, n), 256, 0, stream>>>(bt);
  };
  auto gln = [&](const ushort* A, const ushort* Bt, const float* bias, const float* res,
                 const float* g_, const float* b_, float* of, ushort* ob, int R, int K) {
    gemmln_kernel<<<R / 16, 256, 0, stream>>>(A, Bt, bias, res, g_, b_, of, ob, R, K);
  };

  mask_norm_kernel<<<16, 256, 0, stream>>>(mraw, maskf);

  // weight convert (batched)
  {
    WJobs J;
    const float* Ws[7] = {dc_W, Wq, Wk, Wv, Wd, W1, W2};
    ushort* Ts[7] = {dcWt, WqT, WkT, WvT, WdT, W1T, W2T};
    int Ks[7] = {256, 256, 256, 256, 256, 256, 1024};
    int Cs[7] = {256, 256, 256, 256, 256, 1024, 256};
    int Ls[7] = {1, 4, 4, 4, 4, 4, 4};
    int off = 0;
    for (int j = 0; j < 7; ++j) {
      J.W[j] = Ws[j]; J.Wt[j] = Ts[j]; J.K[j] = Ks[j]; J.C[j] = Cs[j]; J.off[j] = off;
      off += (Ks[j] / 32) * (Cs[j] / 32) * Ls[j];
    }
    wconv_all_kernel<<<off, 256, 0, stream>>>(J);
  }

  // encoders (single gln over 5120 rows: qs rows then ks rows, adjacent outputs)
  encode2_kernel<<<kB * (kM + kN), 256, 0, stream>>>(qc2, qf2, qf3, kc2, kf2, kf3,
                                                     ln1_g, ln1_b, encT);
  gln(encT, dcWt, dc_b, nullptr, dcln_g, dcln_b, qs_s, qs_b, kB * (kM + kN), 256);
  cls_init_kernel<<<2, 256, 0, stream>>>(cls_f, cls_s);

  for (int i = 0; i < kL; ++i) {
    const ushort* Wq_i = WqT + (size_t)i * 65536;  const float* bq_i = bq + i * 256;
    const ushort* Wk_i = WkT + (size_t)i * 65536;  const float* bk_i = bk + i * 256;
    const ushort* Wv_i = WvT + (size_t)i * 65536;  const float* bv_i = bv + i * 256;
    const ushort* Wd_i = WdT + (size_t)i * 65536;  const float* bd_i = bd + i * 256;
    const float* ag_i = aln_g + i * 256;           const float* ab_i = aln_b + i * 256;
    const ushort* W1_i = W1T + (size_t)i * 262144; const float* b1_i = b1 + i * 1024;
    const ushort* W2_i = W2T + (size_t)i * 262144; const float* b2_i = b2 + i * 256;
    const float* fg_i = fln_g + i * 256;           const float* fb_i = fln_b + i * 256;
    int Rk = kB * kN, Rq = kB * kM;

    // ---- ks sublayer ----
    {
      GDesc ds[3] = {
        mk(ks_b, Wq_i, bq_i, nullptr, Qb,  Rk, 256, 256, 2, Rk, Rk, 0, 0),
        mk(ks_b, Wk_i, bk_i, nullptr, Kks, Rk, 256, 256, 2, Rk, Rk, 0, 0),
        mk(ks_b, Wv_i, bv_i, nullptr, Vt_ks, Rk, 256, 256, 4, kN, 0, 0, kN)};
      launch(ds, 3);
    }
    attn6_kernel<<<dim3(kB * 8, kN / 64, 2), 256, 0, stream>>>(
        Qb, Kks, Vt_ks, ksPart, maskf, kN, kN, kN, -1, kN / 2, 2);
    combine_kernel<<<kB * 8 * kN / 8, 256, 0, stream>>>(ksPart, AOb, kN, 2);
    gln(AOb, Wd_i, bd_i, ks_s, ag_i, ab_i, Ta, T2b, Rk, 256);
    { GDesc d = mk(T2b, W1_i, b1_i, nullptr, FFb, Rk, 256, 1024, 1 | 2, Rk, Rk, 0, 0);
      launch(&d, 1); }
    gln(FFb, W2_i, b2_i, Ta, fg_i, fb_i, ks_s, ks_b, Rk, 1024);

    // ---- qs sublayer (query_self, keys = new ks) ----
    {
      GDesc ds[5] = {
        mk(qs_b, Wq_i, bq_i, nullptr, Qb, Rq, 256, 256, 2, Rq, Rq, 0, 0),
        mk(ks_b, Wk_i, bk_i, nullptr, Kbig, Rk, 256, 256, 2, kN, kKV, 0, 0),
        mk(ks_b, Wv_i, bv_i, nullptr, Vt_big, Rk, 256, 256, 4, kN, 0, 0, kKV),
        mk(qs_b, Wk_i, bk_i, nullptr, Kbig, Rq, 256, 256, 2, kM, kKV, kN, 0),
        mk(qs_b, Wv_i, bv_i, nullptr, Vt_big, Rq, 256, 256, 4, kM, 0, kN, kKV)};
      launch(ds, 5);
    }
    attn6_kernel<<<dim3(kB * 8, kM / 64, 4), 256, 0, stream>>>(
        Qb, Kbig, Vt_big, qsPart, maskf, kM, kKV, kKV, kN, kN / 4, 4);
    combine_kernel<<<kB * 8 * kM / 8, 256, 0, stream>>>(qsPart, AOb, kM, 4);
    gln(AOb, Wd_i, bd_i, qs_s, ag_i, ab_i, Ta, T2b, Rq, 256);
    { GDesc d = mk(T2b, W1_i, b1_i, nullptr, FFb, Rq, 256, 1024, 1 | 2, Rq, Rq, 0, 0);
      launch(&d, 1); }
    gln(FFb, W2_i, b2_i, Ta, fg_i, fb_i, qs_s, qs_b, Rq, 1024);

    // ---- cls sublayer ----
    {
      GDesc ds[2] = {
        mk(qs_b, Wk_i, bk_i, nullptr, Kbig, Rq, 256, 256, 2, kM, kKV, kN, 0),
        mk(qs_b, Wv_i, bv_i, nullptr, Vt_big, Rq, 256, 256, 4, kM, 0, kN, kKV)};
      launch(ds, 2);
    }
    cls_attn_kernel<<<16, 256, 0, stream>>>(cls_s, Wq_i, bq_i, Wk_i,
                                            bk_i, Wv_i, bv_i,
                                            Kbig, Vt_big, AOc);
    cls_mlp_kernel<<<2, 1024, 0, stream>>>(AOc, cls_s, Wd_i, bd_i, ag_i, ab_i,
                                           W1_i, b1_i, W2_i, b2_i, fg_i, fb_i);
  }

  copyout_kernel<<<5122, 256, 0, stream>>>(qs_s, ks_s, cls_s, (float*)d_out);
}

// Round 14
// 831.610 us; speedup vs baseline: 1.0067x; 1.0067x over previous
//
#include <hip/hip_runtime.h>
#include <math.h>

namespace {
constexpr int kB = 2;
constexpr int kM = 512;
constexpr int kN = 2048;
constexpr int kHID = 256;
constexpr int kDH = 32;
constexpr int kL = 4;
constexpr float kEPS = 1e-5f;
constexpr int kKV = 2560; // Kbig rows / Vt_big cols per batch (2048 ks + 512 qs)
}

typedef __attribute__((ext_vector_type(8))) short short8;
typedef __attribute__((ext_vector_type(4))) float f32x4;

__device__ inline ushort f2b(float f) {
  unsigned u = __builtin_bit_cast(unsigned, f);
  unsigned r = (u + 0x7fffu + ((u >> 16) & 1u)) >> 16;
  return (ushort)r;
}
__device__ inline float b2f(ushort u) {
  return __builtin_bit_cast(float, (unsigned)u << 16);
}
__device__ inline unsigned cvtpk(float lo, float hi) {
  unsigned r;
  asm("v_cvt_pk_bf16_f32 %0, %1, %2" : "=v"(r) : "v"(lo), "v"(hi));
  return r;
}
__device__ inline void gld16(ushort* lds, const ushort* g) {
  __builtin_amdgcn_global_load_lds(
      (const __attribute__((address_space(1))) void*)g,
      (__attribute__((address_space(3))) void*)lds, 16, 0, 0);
}

// dot of 8 bf16 weights with 8 f32 activations from LDS
__device__ inline float dot8(const float* a, short8 w) {
  float s = 0.f;
  #pragma unroll
  for (int jj = 0; jj < 8; ++jj) s += a[jj] * b2f((ushort)w[jj]);
  return s;
}

// ---------------- mask normalization (dtype sniffing) -> additive mask ----------------
__global__ __launch_bounds__(256) void mask_norm_kernel(
    const unsigned char* __restrict__ mraw, float* __restrict__ mf)
{
  int tid = threadIdx.x;
  __shared__ unsigned sh[4];
  if (tid < 4) sh[tid] = 0;
  __syncthreads();
  unsigned l1 = 0, l2 = 0, l3 = 0, l4 = 0;
  for (int j = 0; j < 16; ++j) {
    int p = tid * 16 + j;
    unsigned v = mraw[p];
    int r = p & 3;
    if (r == 1) l1 |= v;
    else if (r == 2) l2 |= v;
    else if (r == 3) l3 |= v;
    else if ((p & 7) == 4) l4 |= v;
  }
  if (l1) atomicOr(&sh[0], l1);
  if (l2) atomicOr(&sh[1], l2);
  if (l3) atomicOr(&sh[2], l3);
  if (l4) atomicOr(&sh[3], l4);
  __syncthreads();
  unsigned a1 = sh[0], a2 = sh[1], a3 = sh[2], a4 = sh[3];
  int mode; // 0=u8, 1=i32, 2=i64, 3=f32
  if ((a1 | a2 | a3) == 0) mode = a4 ? 1 : 2;
  else if (a1 == 0 && (a2 & ~0x80u) == 0 && (a3 & ~0x3Fu) == 0 && ((a2 | a3) != 0))
    mode = 3;
  else mode = 0;

  int i = blockIdx.x * 256 + tid;
  unsigned char v;
  if (mode == 0) v = mraw[i];
  else if (mode == 1) v = mraw[i * 4];
  else if (mode == 2) v = mraw[i * 8];
  else v = mraw[i * 4 + 3];
  mf[i] = v ? 0.f : -2.5505654e9f; // -(1e10 * scale2)
}

// ---------------- unified encoder: sinenc + add + LN1 -> bf16 ----------------
__global__ __launch_bounds__(256) void encode2_kernel(
    const float* __restrict__ qc2, const float* __restrict__ qf2,
    const float* __restrict__ qf3, const float* __restrict__ kc2,
    const float* __restrict__ kf2, const float* __restrict__ kf3,
    const float* __restrict__ g, const float* __restrict__ bb,
    ushort* __restrict__ out)
{
  int row = blockIdx.x; // 0..5119
  const float *c2d, *f2, *f3;
  int r;
  if (row < kB * kM) { c2d = qc2; f2 = qf2; f3 = qf3; r = row; }
  else { c2d = kc2; f2 = kf2; f3 = kf3; r = row - kB * kM; }
  int c = threadIdx.x;
  float coord = c2d[(size_t)r * 2 + (c >> 7)];
  int h = c & 127;
  float ex = (float)(h & ~1) * (1.0f / 128.0f);
  float inv = expf(ex * 9.210340371976184f);
  float val = coord / inv;
  float e = (h & 1) ? cosf(val) : sinf(val);
  float x = f2[(size_t)r * 256 + c] + f3[(size_t)r * 256 + c] + e;
  __shared__ float red[256];
  red[c] = x; __syncthreads();
  for (int s = 128; s > 0; s >>= 1) { if (c < s) red[c] += red[c + s]; __syncthreads(); }
  float mean = red[0] * (1.0f / 256.0f);
  __syncthreads();
  float d = x - mean;
  red[c] = d * d; __syncthreads();
  for (int s = 128; s > 0; s >>= 1) { if (c < s) red[c] += red[c + s]; __syncthreads(); }
  float var = red[0] * (1.0f / 256.0f);
  out[(size_t)row * 256 + c] = f2b(d * rsqrtf(var + kEPS) * g[c] + bb[c]);
}

// ---------------- batched weight convert + transpose ----------------
struct WJobs {
  const float* W[7]; ushort* Wt[7];
  int K[7], C[7], off[7];
};
__global__ __launch_bounds__(256) void wconv_all_kernel(WJobs J)
{
  __shared__ float t[32][33];
  int bid = blockIdx.x;
  int j = 0;
  #pragma unroll
  for (int q = 1; q < 7; ++q) if (bid >= J.off[q]) j = q;
  int tl = bid - J.off[j];
  int K = J.K[j], C = J.C[j];
  int tpl = (K >> 5) * (C >> 5);
  int layer = tl / tpl, rem = tl - layer * tpl;
  int kt = rem % (K >> 5), ct = rem / (K >> 5);
  const float* Wl = J.W[j] + (size_t)layer * K * C;
  ushort* Wtl = J.Wt[j] + (size_t)layer * K * C;
  int k0 = kt * 32, c0 = ct * 32;
  int tx = threadIdx.x & 31, ty = threadIdx.x >> 5;
  for (int i = ty; i < 32; i += 8) t[i][tx] = Wl[(size_t)(k0 + i) * C + c0 + tx];
  __syncthreads();
  for (int i = ty; i < 32; i += 8)
    Wtl[(size_t)(c0 + i) * K + k0 + tx] = f2b(t[tx][i]);
}

// ---------------- batched bf16 MFMA GEMM (64x64 tiles) ----------------
struct GDesc {
  const ushort* A; const ushort* Bt; const float* bias; const float* res; void* out;
  int R, K, C, flags;          // flags: 1 relu, 2 bf16-out, 4 transposed-Vt-out
  int in_rpb, out_rpb, out_off, vt_stride;
};
struct GBatch { GDesc d[5]; };

__global__ __launch_bounds__(256) void gemmx_kernel(GBatch bt)
{
  GDesc d = bt.d[blockIdx.z];
  int r0 = blockIdx.x * 64;
  if (r0 >= d.R) return;
  int c0 = blockIdx.y * 64;

  __shared__ ushort As[4096];
  __shared__ ushort Bs[4096];
  int tid = threadIdx.x;
  int lam = tid & 63, wv = tid >> 6;
  int wr = wv >> 1, wc = wv & 1;
  int K = d.K;
  int srow8 = lam >> 3;
  int sxor = (lam & 7) ^ srow8;

  f32x4 acc[2][2] = {};

  for (int k0 = 0; k0 < K; k0 += 64) {
    #pragma unroll
    for (int i = 0; i < 2; ++i) {
      int row = 16 * wv + 8 * i + srow8;
      gld16(As + wv * 1024 + i * 512,
            d.A + (size_t)(r0 + row) * K + k0 + 8 * sxor);
      gld16(Bs + wv * 1024 + i * 512,
            d.Bt + (size_t)(c0 + row) * K + k0 + 8 * sxor);
    }
    __syncthreads();
    #pragma unroll
    for (int ks = 0; ks < 2; ++ks) {
      short8 af[2], bf_[2];
      #pragma unroll
      for (int m = 0; m < 2; ++m) {
        int ra = wr * 32 + m * 16 + (lam & 15);
        int ch = (ks * 4 + (lam >> 4)) ^ (ra & 7);
        af[m] = *(const short8*)(As + ra * 64 + ch * 8);
      }
      #pragma unroll
      for (int n = 0; n < 2; ++n) {
        int rb = wc * 32 + n * 16 + (lam & 15);
        int ch = (ks * 4 + (lam >> 4)) ^ (rb & 7);
        bf_[n] = *(const short8*)(Bs + rb * 64 + ch * 8);
      }
      #pragma unroll
      for (int m = 0; m < 2; ++m)
        #pragma unroll
        for (int n = 0; n < 2; ++n)
          acc[m][n] = __builtin_amdgcn_mfma_f32_16x16x32_bf16(
              af[m], bf_[n], acc[m][n], 0, 0, 0);
    }
    __syncthreads();
  }

  if (!(d.flags & 4)) {
    #pragma unroll
    for (int m = 0; m < 2; ++m) {
      #pragma unroll
      for (int reg = 0; reg < 4; ++reg) {
        int gr = r0 + wr * 32 + m * 16 + (lam >> 4) * 4 + reg;
        int bidx = gr / d.in_rpb, rr = gr - bidx * d.in_rpb;
        size_t orow = (size_t)bidx * d.out_rpb + d.out_off + rr;
        #pragma unroll
        for (int n = 0; n < 2; ++n) {
          int gc = c0 + wc * 32 + n * 16 + (lam & 15);
          float v = acc[m][n][reg] + d.bias[gc];
          if (d.res) v += d.res[(size_t)gr * d.C + gc];
          if (d.flags & 1) v = fmaxf(v, 0.f);
          if (d.flags & 2) ((ushort*)d.out)[orow * d.C + gc] = f2b(v);
          else ((float*)d.out)[orow * d.C + gc] = v;
        }
      }
    }
  } else {
    #pragma unroll
    for (int m = 0; m < 2; ++m)
      #pragma unroll
      for (int n = 0; n < 2; ++n)
        #pragma unroll
        for (int reg = 0; reg < 4; ++reg) {
          int col = wc * 32 + n * 16 + (lam & 15);
          int row = wr * 32 + m * 16 + (lam >> 4) * 4 + reg;
          float v = acc[m][n][reg] + d.bias[c0 + col];
          As[col * 64 + (((row >> 3) ^ (col & 7)) << 3) + (row & 7)] = f2b(v);
        }
    __syncthreads();
    int col2 = tid >> 2, rc = tid & 3;
    #pragma unroll
    for (int u = 0; u < 2; ++u) {
      int rowc = rc * 2 + u;
      short8 val = *(const short8*)(As + col2 * 64 + ((rowc ^ (col2 & 7)) << 3));
      int r = r0 + rowc * 8;
      int bidx = r / d.in_rpb, rr = r - bidx * d.in_rpb;
      *(short8*)((ushort*)d.out +
                 ((size_t)bidx * 256 + c0 + col2) * d.vt_stride + d.out_off + rr) = val;
    }
  }
}

// ---------------- fused GEMM + bias (+res) + LayerNorm: 16-row x 256-col blocks ----------------
__global__ __launch_bounds__(256) void gemmln_kernel(
    const ushort* __restrict__ A, const ushort* __restrict__ Bt,
    const float* __restrict__ bias, const float* __restrict__ res,
    const float* __restrict__ g, const float* __restrict__ bb,
    float* __restrict__ outf, ushort* __restrict__ outb, int R, int K)
{
  __shared__ ushort As[16 * 64];
  __shared__ ushort Bs[256 * 64];
  __shared__ float redL[16][4];
  int r0 = blockIdx.x * 16;
  int tid = threadIdx.x;
  int lam = tid & 63, wv = tid >> 6;
  int srow8 = lam >> 3;
  int sxor = (lam & 7) ^ srow8;

  f32x4 acc[4] = {};

  for (int k0 = 0; k0 < K; k0 += 64) {
    if (wv < 2)
      gld16(As + wv * 512, A + (size_t)(r0 + wv * 8 + srow8) * K + k0 + 8 * sxor);
    #pragma unroll
    for (int j = 0; j < 8; ++j) {
      int cc = wv * 8 + j;
      gld16(Bs + cc * 512, Bt + (size_t)(cc * 8 + srow8) * K + k0 + 8 * sxor);
    }
    __syncthreads();
    #pragma unroll
    for (int ks = 0; ks < 2; ++ks) {
      int ra = lam & 15;
      int cha = (ks * 4 + (lam >> 4)) ^ (ra & 7);
      short8 af = *(const short8*)(As + ra * 64 + cha * 8);
      #pragma unroll
      for (int cg = 0; cg < 4; ++cg) {
        int rb = wv * 64 + cg * 16 + (lam & 15);
        int chb = (ks * 4 + (lam >> 4)) ^ (rb & 7);
        short8 bf_ = *(const short8*)(Bs + rb * 64 + chb * 8);
        acc[cg] = __builtin_amdgcn_mfma_f32_16x16x32_bf16(af, bf_, acc[cg], 0, 0, 0);
      }
    }
    __syncthreads();
  }

  int col_lo = lam & 15, rsel = lam >> 4;
  float v[4][4];
  #pragma unroll
  for (int cg = 0; cg < 4; ++cg) {
    int col = wv * 64 + cg * 16 + col_lo;
    float bi = bias[col];
    #pragma unroll
    for (int reg = 0; reg < 4; ++reg) {
      int row = r0 + rsel * 4 + reg;
      float x = acc[cg][reg] + bi;
      if (res) x += res[(size_t)row * 256 + col];
      v[cg][reg] = x;
    }
  }
  float mean[4];
  {
    float ps[4];
    #pragma unroll
    for (int reg = 0; reg < 4; ++reg) {
      ps[reg] = v[0][reg] + v[1][reg] + v[2][reg] + v[3][reg];
      #pragma unroll
      for (int o = 1; o < 16; o <<= 1) ps[reg] += __shfl_xor(ps[reg], o);
    }
    if (col_lo == 0)
      #pragma unroll
      for (int reg = 0; reg < 4; ++reg) redL[rsel * 4 + reg][wv] = ps[reg];
    __syncthreads();
    #pragma unroll
    for (int reg = 0; reg < 4; ++reg) {
      int rr = rsel * 4 + reg;
      mean[reg] = (redL[rr][0] + redL[rr][1] + redL[rr][2] + redL[rr][3]) * (1.0f / 256.0f);
    }
    __syncthreads();
  }
  float rs_[4];
  {
    float ps[4];
    #pragma unroll
    for (int reg = 0; reg < 4; ++reg) {
      float s = 0.f;
      #pragma unroll
      for (int cg = 0; cg < 4; ++cg) {
        float dd = v[cg][reg] - mean[reg];
        s += dd * dd;
      }
      ps[reg] = s;
      #pragma unroll
      for (int o = 1; o < 16; o <<= 1) ps[reg] += __shfl_xor(ps[reg], o);
    }
    if (col_lo == 0)
      #pragma unroll
      for (int reg = 0; reg < 4; ++reg) redL[rsel * 4 + reg][wv] = ps[reg];
    __syncthreads();
    #pragma unroll
    for (int reg = 0; reg < 4; ++reg) {
      int rr = rsel * 4 + reg;
      float var = (redL[rr][0] + redL[rr][1] + redL[rr][2] + redL[rr][3]) * (1.0f / 256.0f);
      rs_[reg] = rsqrtf(var + kEPS);
    }
  }
  #pragma unroll
  for (int cg = 0; cg < 4; ++cg) {
    int col = wv * 64 + cg * 16 + col_lo;
    float gg = g[col], bv = bb[col];
    #pragma unroll
    for (int reg = 0; reg < 4; ++reg) {
      int row = r0 + rsel * 4 + reg;
      float y = (v[cg][reg] - mean[reg]) * rs_[reg] * gg + bv;
      outf[(size_t)row * 256 + col] = y;
      outb[(size_t)row * 256 + col] = f2b(y);
    }
  }
}

// ---------------- MFMA flash attention v6: LDS-shared K/V^T, split-K, shfl-P ----------------
__global__ __launch_bounds__(256) void attn6_kernel(
    const ushort* __restrict__ Qp, const ushort* __restrict__ Kp,
    const ushort* __restrict__ Vt, float* __restrict__ Pp,
    const float* __restrict__ madd,
    int Sq, int k_rpb, int vt_stride, int self_off, int slen, int ns)
{
  __shared__ ushort KsL[64 * 32];  // [key][chunk^((key>>1)&3)]
  __shared__ ushort VtL[32 * 64];  // [d][chunk^(d&7)]
  int bh = blockIdx.x;
  int b = bh >> 3, h = bh & 7;
  int sidx = blockIdx.z;
  int tid = threadIdx.x;
  int lane = tid & 63;
  int qlane = lane & 15, g = lane >> 4;
  int gq = blockIdx.y * 64 + (tid >> 6) * 16 + qlane;
  const float scale2 = 0.17677669529663688f * 1.4426950408889634f;

  short8 qB = *(const short8*)(Qp + ((size_t)(b * Sq + gq)) * 256 + h * 32 + g * 8);

  float mi = -3.0e38f, li = 0.f;
  f32x4 acc0 = {}, acc1 = {};

  if (self_off >= 0 && sidx == 0) {
    const ushort* kr = Kp + ((size_t)(b * k_rpb + self_off + gq)) * 256 + h * 32 + g * 8;
    short8 k8 = *(const short8*)kr;
    float part = 0.f;
    #pragma unroll
    for (int j = 0; j < 8; ++j) part += b2f((ushort)qB[j]) * b2f((ushort)k8[j]);
    part += __shfl_xor(part, 16);
    part += __shfl_xor(part, 32);
    mi = part * scale2;
    li = 1.f;
    const ushort* vb = Vt + ((size_t)(b * 256 + h * 32)) * vt_stride + self_off + gq;
    #pragma unroll
    for (int r = 0; r < 4; ++r) {
      acc0[r] = b2f(vb[(size_t)(4 * g + r) * vt_stride]);
      acc1[r] = b2f(vb[(size_t)(16 + 4 * g + r) * vt_stride]);
    }
  }

  const float* mb = madd + (size_t)b * kN;
  int skey = tid >> 2, sc = tid & 3;   // K staging: key row, 8-elem chunk
  int sd = tid >> 3, sc8 = tid & 7;    // V^T staging: d row, 8-key chunk
  const ushort* Ksrc = Kp + ((size_t)(b * k_rpb + skey)) * 256 + h * 32 + sc * 8;
  const ushort* Vsrc = Vt + ((size_t)(b * 256 + h * 32 + sd)) * vt_stride + sc8 * 8;
  ushort* Kdst = KsL + skey * 32 + ((sc ^ ((skey >> 1) & 3)) << 3);
  ushort* Vdst = VtL + sd * 64 + ((sc8 ^ (sd & 7)) << 3);

  int base = sidx * slen;
  int ntile = slen >> 6;

  for (int it = 0; it < ntile; ++it) {
    int n0 = base + it * 64;
    __syncthreads();  // prev tile's LDS reads complete
    *(short8*)Kdst = *(const short8*)(Ksrc + (size_t)n0 * 256);
    *(short8*)Vdst = *(const short8*)(Vsrc + n0);
    __syncthreads();

    float4 m4[4];
    #pragma unroll
    for (int f = 0; f < 4; ++f)
      m4[f] = *(const float4*)(mb + n0 + 16 * f + 4 * g);

    f32x4 st[4];
    __builtin_amdgcn_s_setprio(1);
    #pragma unroll
    for (int f = 0; f < 4; ++f) {
      int key = f * 16 + qlane;
      short8 kf = *(const short8*)(KsL + key * 32 + ((g ^ ((key >> 1) & 3)) << 3));
      st[f] = __builtin_amdgcn_mfma_f32_16x16x32_bf16(
          kf, qB, (f32x4){0.f, 0.f, 0.f, 0.f}, 0, 0, 0);
    }
    __builtin_amdgcn_s_setprio(0);

    float p[4][4];
    float tm = -3.0e38f;
    #pragma unroll
    for (int f = 0; f < 4; ++f) {
      float mm[4] = {m4[f].x, m4[f].y, m4[f].z, m4[f].w};
      #pragma unroll
      for (int r = 0; r < 4; ++r) {
        float s = fmaf(st[f][r], scale2, mm[r]);
        p[f][r] = s;
        tm = fmaxf(tm, s);
      }
    }
    tm = fmaxf(tm, __shfl_xor(tm, 16));
    tm = fmaxf(tm, __shfl_xor(tm, 32));
    if (__any(tm > mi + 11.5f)) {  // defer-max
      float nm = fmaxf(mi, tm);
      float fs = exp2f(mi - nm);
      li *= fs; mi = nm;
      #pragma unroll
      for (int r = 0; r < 4; ++r) { acc0[r] *= fs; acc1[r] *= fs; }
    }
    float ls = 0.f;
    #pragma unroll
    for (int f = 0; f < 4; ++f)
      #pragma unroll
      for (int r = 0; r < 4; ++r) {
        float pv = exp2f(p[f][r] - mi);
        p[f][r] = pv;
        ls += pv;
      }
    ls += __shfl_xor(ls, 16);
    ls += __shfl_xor(ls, 32);
    li += ls;

    // P^T -> bf16 B-fragments via pack + 8 shfl per 32-key half
    unsigned pkw[4][2];
    #pragma unroll
    for (int f = 0; f < 4; ++f) {
      pkw[f][0] = cvtpk(p[f][0], p[f][1]);
      pkw[f][1] = cvtpk(p[f][2], p[f][3]);
    }
    int src0 = qlane | ((2 * (g & 1)) << 4);
    int src1 = src0 + 16;
    bool hi = g >= 2;
    #pragma unroll
    for (int t = 0; t < 2; ++t) {
      unsigned t0 = (unsigned)__shfl((int)pkw[2 * t][0], src0);
      unsigned t1 = (unsigned)__shfl((int)pkw[2 * t][1], src0);
      unsigned t2 = (unsigned)__shfl((int)pkw[2 * t][0], src1);
      unsigned t3 = (unsigned)__shfl((int)pkw[2 * t][1], src1);
      unsigned u0 = (unsigned)__shfl((int)pkw[2 * t + 1][0], src0);
      unsigned u1 = (unsigned)__shfl((int)pkw[2 * t + 1][1], src0);
      unsigned u2 = (unsigned)__shfl((int)pkw[2 * t + 1][0], src1);
      unsigned u3 = (unsigned)__shfl((int)pkw[2 * t + 1][1], src1);
      union { unsigned u[4]; short8 v; } pb;
      pb.u[0] = hi ? u0 : t0;
      pb.u[1] = hi ? u1 : t1;
      pb.u[2] = hi ? u2 : t2;
      pb.u[3] = hi ? u3 : t3;
      __builtin_amdgcn_s_setprio(1);
      int d0 = qlane, d1 = 16 + qlane;
      short8 vf0 = *(const short8*)(VtL + d0 * 64 + (((t * 4 + g) ^ (d0 & 7)) << 3));
      acc0 = __builtin_amdgcn_mfma_f32_16x16x32_bf16(vf0, pb.v, acc0, 0, 0, 0);
      short8 vf1 = *(const short8*)(VtL + d1 * 64 + (((t * 4 + g) ^ (d1 & 7)) << 3));
      acc1 = __builtin_amdgcn_mfma_f32_16x16x32_bf16(vf1, pb.v, acc1, 0, 0, 0);
      __builtin_amdgcn_s_setprio(0);
    }
  }

  float* rec = Pp + ((size_t)(bh * Sq + gq) * ns + sidx) * 20;
  if (g == 0) { rec[0] = mi; rec[1] = li; }
  ushort* accp = (ushort*)(rec + 2);
  uint2 w0, w1;
  w0.x = cvtpk(acc0[0], acc0[1]); w0.y = cvtpk(acc0[2], acc0[3]);
  w1.x = cvtpk(acc1[0], acc1[1]); w1.y = cvtpk(acc1[2], acc1[3]);
  *(uint2*)(accp + 4 * g) = w0;
  *(uint2*)(accp + 16 + 4 * g) = w1;
}

// ---------------- split-K combine: merge ns partials, write bf16 AO ----------------
__global__ __launch_bounds__(256) void combine_kernel(
    const float* __restrict__ Pp, ushort* __restrict__ AO, int Sq, int ns)
{
  int r = blockIdx.x * 8 + (threadIdx.x >> 5);
  int d = threadIdx.x & 31;
  int bh = r / Sq, q = r - bh * Sq;
  int b = bh >> 3, h = bh & 7;
  const float* rb = Pp + (size_t)r * ns * 20;
  float M = -3.0e38f;
  for (int s2 = 0; s2 < ns; ++s2) M = fmaxf(M, rb[s2 * 20]);
  float L = 0.f, O = 0.f;
  for (int s2 = 0; s2 < ns; ++s2) {
    float w = exp2f(rb[s2 * 20] - M);
    L += rb[s2 * 20 + 1] * w;
    O += w * b2f(((const ushort*)(rb + s2 * 20 + 2))[d]);
  }
  AO[((size_t)(b * Sq + q)) * 256 + h * 32 + d] = f2b(O / L);
}

// ---------------- fused cls attention (one block per (b,h)) ----------------
__global__ __launch_bounds__(256) void cls_attn_kernel(
    const float* __restrict__ cls_s,
    const ushort* __restrict__ WqT, const float* __restrict__ bq,
    const ushort* __restrict__ WkT, const float* __restrict__ bk,
    const ushort* __restrict__ WvT, const float* __restrict__ bv,
    const ushort* __restrict__ Kbig, const ushort* __restrict__ Vt,
    float* __restrict__ AOc)
{
  __shared__ float c0f[256], qv[32], k0v[32], v0v[32];
  __shared__ float red[256];
  __shared__ float sarr[2560];
  __shared__ float scl[4];
  const float scale2 = 0.17677669529663688f * 1.4426950408889634f;
  int b = blockIdx.x >> 3, h = blockIdx.x & 7;
  int t = threadIdx.x;
  c0f[t] = cls_s[b * 256 + t];
  __syncthreads();

  const ushort* Wm[3] = {WqT, WkT, WvT};
  const float* Bi[3] = {bq, bk, bv};
  float* Ov[3] = {qv, k0v, v0v};
  for (int pi = 0; pi < 3; ++pi) {
    int d = t >> 3, sl = t & 7;
    const ushort* wrow = Wm[pi] + (size_t)(h * 32 + d) * 256 + sl * 32;
    float part = 0.f;
    #pragma unroll
    for (int j = 0; j < 32; j += 8) {
      short8 w8 = *(const short8*)(wrow + j);
      #pragma unroll
      for (int jj = 0; jj < 8; ++jj) part += c0f[sl * 32 + j + jj] * b2f((ushort)w8[jj]);
    }
    red[t] = part;
    __syncthreads();
    if (t < 32) {
      float sum = 0.f;
      #pragma unroll
      for (int s = 0; s < 8; ++s) sum += red[t * 8 + s];
      Ov[pi][t] = sum + Bi[pi][h * 32 + t];
    }
    __syncthreads();
  }

  if (t < 32) red[t] = qv[t] * k0v[t];
  __syncthreads();
  if (t == 0) {
    float sc = 0.f;
    for (int j = 0; j < 32; ++j) sc += red[j];
    scl[0] = sc * scale2;
  }
  __syncthreads();

  float lmax = -3.0e38f;
  for (int it = 0; it < 10; ++it) {
    int key = t + it * 256;
    const ushort* krow = Kbig + ((size_t)(b * kKV + key)) * 256 + h * 32;
    float sdot = 0.f;
    #pragma unroll
    for (int j = 0; j < 4; ++j) {
      short8 k8 = ((const short8*)krow)[j];
      #pragma unroll
      for (int jj = 0; jj < 8; ++jj) sdot += qv[j * 8 + jj] * b2f((ushort)k8[jj]);
    }
    sdot *= scale2;
    sarr[key] = sdot;
    lmax = fmaxf(lmax, sdot);
  }
  red[t] = lmax;
  __syncthreads();
  for (int s = 128; s > 0; s >>= 1) { if (t < s) red[t] = fmaxf(red[t], red[t + s]); __syncthreads(); }
  if (t == 0) scl[1] = fmaxf(red[0], scl[0]);
  __syncthreads();
  float M = scl[1];
  float lsum = 0.f;
  for (int it = 0; it < 10; ++it) {
    int key = t + it * 256;
    float pv = exp2f(sarr[key] - M);
    sarr[key] = pv;
    lsum += pv;
  }
  red[t] = lsum;
  __syncthreads();
  for (int s = 128; s > 0; s >>= 1) { if (t < s) red[t] += red[t + s]; __syncthreads(); }
  if (t == 0) {
    scl[3] = exp2f(scl[0] - M);
    scl[2] = red[0] + scl[3];
  }
  __syncthreads();

  {
    int d = t & 31, sl = t >> 5;
    const ushort* vrow = Vt + ((size_t)(b * 256 + h * 32 + d)) * kKV + sl * 320;
    float acc = 0.f;
    for (int j = 0; j < 320; j += 8) {
      short8 v8 = *(const short8*)(vrow + j);
      #pragma unroll
      for (int jj = 0; jj < 8; ++jj) acc += sarr[sl * 320 + j + jj] * b2f((ushort)v8[jj]);
    }
    red[sl * 32 + d] = acc;
  }
  __syncthreads();
  if (t < 32) {
    float o = scl[3] * v0v[t];
    #pragma unroll
    for (int s = 0; s < 8; ++s) o += red[s * 32 + t];
    AOc[b * 256 + h * 32 + t] = o / scl[2];
  }
}

// ---------------- fused cls MLP (1024 threads, 8-lane-per-row coalesced reads) ----------------
__device__ inline float blk_sum1024(float v, float* red, int t) {
  red[t] = v; __syncthreads();
  for (int s = 512; s > 0; s >>= 1) {
    if (t < s) red[t] += red[t + s];
    __syncthreads();
  }
  float r = red[0];
  __syncthreads();
  return r;
}

__global__ __launch_bounds__(1024) void cls_mlp_kernel(
    const float* __restrict__ AOc, float* __restrict__ cls_s,
    const ushort* __restrict__ WdT, const float* __restrict__ bd,
    const float* __restrict__ ag, const float* __restrict__ ab,
    const ushort* __restrict__ W1T, const float* __restrict__ b1,
    const ushort* __restrict__ W2T, const float* __restrict__ b2,
    const float* __restrict__ fg, const float* __restrict__ fb)
{
  __shared__ float oL[256], r0L[256], aL[256], ffL[1024], vL[256], red[1024];
  int b = blockIdx.x, t = threadIdx.x; // 0..1023
  if (t < 256) { oL[t] = AOc[b * 256 + t]; r0L[t] = cls_s[b * 256 + t]; }
  __syncthreads();

  int r8 = t >> 3, c8 = t & 7; // 8 lanes cooperate on one row (coalesced 128B/row)
  // Wd projection (256 rows, K=256): 2 passes of 128 rows
  #pragma unroll
  for (int p = 0; p < 2; ++p) {
    int row = p * 128 + r8;
    const ushort* wr_ = WdT + (size_t)row * 256 + c8 * 8;
    float a0 = 0.f, a1 = 0.f, a2 = 0.f, a3 = 0.f;
    a0 = dot8(oL + c8 * 8, *(const short8*)(wr_));
    a1 = dot8(oL + c8 * 8 + 64, *(const short8*)(wr_ + 64));
    a2 = dot8(oL + c8 * 8 + 128, *(const short8*)(wr_ + 128));
    a3 = dot8(oL + c8 * 8 + 192, *(const short8*)(wr_ + 192));
    float s = (a0 + a1) + (a2 + a3);
    s += __shfl_xor(s, 1);
    s += __shfl_xor(s, 2);
    s += __shfl_xor(s, 4);
    if (c8 == 0) vL[row] = s + bd[row] + r0L[row];
  }
  __syncthreads();
  // LN #1
  {
    float x = (t < 256) ? vL[t] : 0.f;
    float mean = blk_sum1024(x, red, t) * (1.0f / 256.0f);
    float d = (t < 256) ? (vL[t] - mean) : 0.f;
    float var = blk_sum1024(d * d, red, t) * (1.0f / 256.0f);
    float rs = rsqrtf(var + kEPS);
    if (t < 256) aL[t] = d * rs * ag[t] + ab[t];
  }
  __syncthreads();
  // FF1 (1024 rows, K=256) + relu: 8 passes of 128 rows
  #pragma unroll
  for (int p = 0; p < 8; ++p) {
    int row = p * 128 + r8;
    const ushort* w1r = W1T + (size_t)row * 256 + c8 * 8;
    float a0 = dot8(aL + c8 * 8, *(const short8*)(w1r));
    float a1 = dot8(aL + c8 * 8 + 64, *(const short8*)(w1r + 64));
    float a2 = dot8(aL + c8 * 8 + 128, *(const short8*)(w1r + 128));
    float a3 = dot8(aL + c8 * 8 + 192, *(const short8*)(w1r + 192));
    float s = (a0 + a1) + (a2 + a3);
    s += __shfl_xor(s, 1);
    s += __shfl_xor(s, 2);
    s += __shfl_xor(s, 4);
    if (c8 == 0) ffL[row] = fmaxf(s + b1[row], 0.f);
  }
  __syncthreads();
  // FF2 (256 rows, K=1024): 2 passes of 128 rows; 16 chunks per thread
  #pragma unroll
  for (int p = 0; p < 2; ++p) {
    int row = p * 128 + r8;
    const ushort* w2r = W2T + (size_t)row * 1024 + c8 * 8;
    float a0 = 0.f, a1 = 0.f, a2 = 0.f, a3 = 0.f;
    #pragma unroll
    for (int j = 0; j < 1024; j += 256) {
      a0 += dot8(ffL + c8 * 8 + j, *(const short8*)(w2r + j));
      a1 += dot8(ffL + c8 * 8 + j + 64, *(const short8*)(w2r + j + 64));
      a2 += dot8(ffL + c8 * 8 + j + 128, *(const short8*)(w2r + j + 128));
      a3 += dot8(ffL + c8 * 8 + j + 192, *(const short8*)(w2r + j + 192));
    }
    float s = (a0 + a1) + (a2 + a3);
    s += __shfl_xor(s, 1);
    s += __shfl_xor(s, 2);
    s += __shfl_xor(s, 4);
    if (c8 == 0) vL[row] = s + b2[row] + aL[row];
  }
  __syncthreads();
  // LN #2
  {
    float x = (t < 256) ? vL[t] : 0.f;
    float mean = blk_sum1024(x, red, t) * (1.0f / 256.0f);
    float d = (t < 256) ? (vL[t] - mean) : 0.f;
    float var = blk_sum1024(d * d, red, t) * (1.0f / 256.0f);
    float rs = rsqrtf(var + kEPS);
    if (t < 256) cls_s[b * 256 + t] = d * rs * fg[t] + fb[t];
  }
}

__global__ void cls_init_kernel(const float* __restrict__ cf, float* __restrict__ cls)
{
  int i = blockIdx.x * 256 + threadIdx.x;
  cls[i] = cf[i & 255];
}

__global__ __launch_bounds__(256) void copyout_kernel(
    const float* __restrict__ qs, const float* __restrict__ ks,
    const float* __restrict__ cls, float* __restrict__ out)
{
  int i = blockIdx.x * 256 + threadIdx.x;
  float v;
  if (i < 262144) v = qs[i];
  else if (i < 1310720) v = ks[i - 262144];
  else v = cls[i - 1310720];
  out[i] = v;
}

extern "C" void kernel_launch(void* const* d_in, const int* in_sizes, int n_in,
                              void* d_out, int out_size, void* d_ws, size_t ws_size,
                              hipStream_t stream)
{
  const float* qc2    = (const float*)d_in[0];
  const float* qf2    = (const float*)d_in[1];
  const float* qf3    = (const float*)d_in[2];
  const float* kc2    = (const float*)d_in[3];
  const float* kf2    = (const float*)d_in[4];
  const float* kf3    = (const float*)d_in[5];
  const unsigned char* mraw = (const unsigned char*)d_in[6];
  const float* ln1_g  = (const float*)d_in[7];
  const float* ln1_b  = (const float*)d_in[8];
  const float* dc_W   = (const float*)d_in[9];
  const float* dc_b   = (const float*)d_in[10];
  const float* dcln_g = (const float*)d_in[11];
  const float* dcln_b = (const float*)d_in[12];
  const float* cls_f  = (const float*)d_in[13];
  const float* Wq     = (const float*)d_in[14];
  const float* bq     = (const float*)d_in[15];
  const float* Wk     = (const float*)d_in[16];
  const float* bk     = (const float*)d_in[17];
  const float* Wv     = (const float*)d_in[18];
  const float* bv     = (const float*)d_in[19];
  const float* Wd     = (const float*)d_in[20];
  const float* bd     = (const float*)d_in[21];
  const float* aln_g  = (const float*)d_in[22];
  const float* aln_b  = (const float*)d_in[23];
  const float* W1     = (const float*)d_in[24];
  const float* b1     = (const float*)d_in[25];
  const float* W2     = (const float*)d_in[26];
  const float* b2     = (const float*)d_in[27];
  const float* fln_g  = (const float*)d_in[28];
  const float* fln_b  = (const float*)d_in[29];

  float* ws = (float*)d_ws;
  float* maskf = ws + 0;          // 4096 (additive)
  float* qs_s  = ws + 4096;       // 262144   (qs_s and ks_s adjacent!)
  float* ks_s  = ws + 266240;     // 1048576
  float* cls_s = ws + 1314816;    // 512
  float* AOc   = ws + 1315328;    // 512
  float* Scr   = ws + 1316864;
  float* Ta    = Scr;                 // 1048576 ('a' f32)
  float* ksPart = Scr + 1048576;      // ns=4: 16*2048*4*20 = 2621440 (fits exactly)
  float* qsPart = Scr + 1048576;      // ns=4: 16*512*4*20 = 655360 (reuses region)
  ushort* ub   = (ushort*)(ws + 4986880);
  ushort* qs_b   = ub + 0;            // 262144  (qs_b and ks_b adjacent!)
  ushort* ks_b   = ub + 262144;       // 1048576
  ushort* T2b    = ub + 1310720;      // 1048576 ('a' bf16)
  ushort* Kbig   = ub + 2359296;      // 1310720 (B x 2560 x 256)
  ushort* Vt_ks  = ub + 3670016;      // 1048576 (B x 256 x 2048)
  ushort* Vt_big = ub + 4718592;      // 1310720 (B x 256 x 2560)
  ushort* FFb    = ub + 6029312;      // 4194304 (overlays encT|Qb|Kks|AOb)
  ushort* encT   = FFb + 0;           // 1310720 (5120 x 256)
  ushort* Qb     = FFb + 0;           // 1048576
  ushort* Kks    = FFb + 1048576;     // 1048576
  ushort* AOb    = FFb + 2097152;     // 1048576
  ushort* wts    = ub + 10223616;
  ushort* dcWt = wts;
  ushort* WqT  = wts + 65536;
  ushort* WkT  = WqT + 262144;
  ushort* WvT  = WkT + 262144;
  ushort* WdT  = WvT + 262144;
  ushort* W1T  = WdT + 262144;
  ushort* W2T  = W1T + 1048576;
  // total ~44.7 MB

  auto mk = [](const ushort* A, const ushort* Bt, const float* bias, const float* res,
               void* out, int R, int K, int C, int flags,
               int in_rpb, int out_rpb, int out_off, int vt_stride) {
    GDesc g; g.A = A; g.Bt = Bt; g.bias = bias; g.res = res; g.out = out;
    g.R = R; g.K = K; g.C = C; g.flags = flags; g.in_rpb = in_rpb;
    g.out_rpb = out_rpb; g.out_off = out_off; g.vt_stride = vt_stride; return g;
  };
  auto launch = [&](const GDesc* ds, int n) {
    GBatch bt{};
    int maxR = 0;
    for (int i = 0; i < n; ++i) { bt.d[i] = ds[i]; if (ds[i].R > maxR) maxR = ds[i].R; }
    gemmx_kernel<<<dim3(maxR / 64, ds[0].C / 64, n), 256, 0, stream>>>(bt);
  };
  auto gln = [&](const ushort* A, const ushort* Bt, const float* bias, const float* res,
                 const float* g_, const float* b_, float* of, ushort* ob, int R, int K) {
    gemmln_kernel<<<R / 16, 256, 0, stream>>>(A, Bt, bias, res, g_, b_, of, ob, R, K);
  };

  mask_norm_kernel<<<16, 256, 0, stream>>>(mraw, maskf);

  // weight convert (batched)
  {
    WJobs J;
    const float* Ws[7] = {dc_W, Wq, Wk, Wv, Wd, W1, W2};
    ushort* Ts[7] = {dcWt, WqT, WkT, WvT, WdT, W1T, W2T};
    int Ks[7] = {256, 256, 256, 256, 256, 256, 1024};
    int Cs[7] = {256, 256, 256, 256, 256, 1024, 256};
    int Ls[7] = {1, 4, 4, 4, 4, 4, 4};
    int off = 0;
    for (int j = 0; j < 7; ++j) {
      J.W[j] = Ws[j]; J.Wt[j] = Ts[j]; J.K[j] = Ks[j]; J.C[j] = Cs[j]; J.off[j] = off;
      off += (Ks[j] / 32) * (Cs[j] / 32) * Ls[j];
    }
    wconv_all_kernel<<<off, 256, 0, stream>>>(J);
  }

  // encoders (single gln over 5120 rows: qs rows then ks rows, adjacent outputs)
  encode2_kernel<<<kB * (kM + kN), 256, 0, stream>>>(qc2, qf2, qf3, kc2, kf2, kf3,
                                                     ln1_g, ln1_b, encT);
  gln(encT, dcWt, dc_b, nullptr, dcln_g, dcln_b, qs_s, qs_b, kB * (kM + kN), 256);
  cls_init_kernel<<<2, 256, 0, stream>>>(cls_f, cls_s);

  for (int i = 0; i < kL; ++i) {
    const ushort* Wq_i = WqT + (size_t)i * 65536;  const float* bq_i = bq + i * 256;
    const ushort* Wk_i = WkT + (size_t)i * 65536;  const float* bk_i = bk + i * 256;
    const ushort* Wv_i = WvT + (size_t)i * 65536;  const float* bv_i = bv + i * 256;
    const ushort* Wd_i = WdT + (size_t)i * 65536;  const float* bd_i = bd + i * 256;
    const float* ag_i = aln_g + i * 256;           const float* ab_i = aln_b + i * 256;
    const ushort* W1_i = W1T + (size_t)i * 262144; const float* b1_i = b1 + i * 1024;
    const ushort* W2_i = W2T + (size_t)i * 262144; const float* b2_i = b2 + i * 256;
    const float* fg_i = fln_g + i * 256;           const float* fb_i = fln_b + i * 256;
    int Rk = kB * kN, Rq = kB * kM;

    // ---- ks sublayer ----
    {
      GDesc ds[3] = {
        mk(ks_b, Wq_i, bq_i, nullptr, Qb,  Rk, 256, 256, 2, Rk, Rk, 0, 0),
        mk(ks_b, Wk_i, bk_i, nullptr, Kks, Rk, 256, 256, 2, Rk, Rk, 0, 0),
        mk(ks_b, Wv_i, bv_i, nullptr, Vt_ks, Rk, 256, 256, 4, kN, 0, 0, kN)};
      launch(ds, 3);
    }
    attn6_kernel<<<dim3(kB * 8, kN / 64, 4), 256, 0, stream>>>(
        Qb, Kks, Vt_ks, ksPart, maskf, kN, kN, kN, -1, kN / 4, 4);
    combine_kernel<<<kB * 8 * kN / 8, 256, 0, stream>>>(ksPart, AOb, kN, 4);
    gln(AOb, Wd_i, bd_i, ks_s, ag_i, ab_i, Ta, T2b, Rk, 256);
    { GDesc d = mk(T2b, W1_i, b1_i, nullptr, FFb, Rk, 256, 1024, 1 | 2, Rk, Rk, 0, 0);
      launch(&d, 1); }
    gln(FFb, W2_i, b2_i, Ta, fg_i, fb_i, ks_s, ks_b, Rk, 1024);

    // ---- qs sublayer (query_self, keys = new ks) ----
    {
      GDesc ds[5] = {
        mk(qs_b, Wq_i, bq_i, nullptr, Qb, Rq, 256, 256, 2, Rq, Rq, 0, 0),
        mk(ks_b, Wk_i, bk_i, nullptr, Kbig, Rk, 256, 256, 2, kN, kKV, 0, 0),
        mk(ks_b, Wv_i, bv_i, nullptr, Vt_big, Rk, 256, 256, 4, kN, 0, 0, kKV),
        mk(qs_b, Wk_i, bk_i, nullptr, Kbig, Rq, 256, 256, 2, kM, kKV, kN, 0),
        mk(qs_b, Wv_i, bv_i, nullptr, Vt_big, Rq, 256, 256, 4, kM, 0, kN, kKV)};
      launch(ds, 5);
    }
    attn6_kernel<<<dim3(kB * 8, kM / 64, 4), 256, 0, stream>>>(
        Qb, Kbig, Vt_big, qsPart, maskf, kM, kKV, kKV, kN, kN / 4, 4);
    combine_kernel<<<kB * 8 * kM / 8, 256, 0, stream>>>(qsPart, AOb, kM, 4);
    gln(AOb, Wd_i, bd_i, qs_s, ag_i, ab_i, Ta, T2b, Rq, 256);
    { GDesc d = mk(T2b, W1_i, b1_i, nullptr, FFb, Rq, 256, 1024, 1 | 2, Rq, Rq, 0, 0);
      launch(&d, 1); }
    gln(FFb, W2_i, b2_i, Ta, fg_i, fb_i, qs_s, qs_b, Rq, 1024);

    // ---- cls sublayer ----
    {
      GDesc ds[2] = {
        mk(qs_b, Wk_i, bk_i, nullptr, Kbig, Rq, 256, 256, 2, kM, kKV, kN, 0),
        mk(qs_b, Wv_i, bv_i, nullptr, Vt_big, Rq, 256, 256, 4, kM, 0, kN, kKV)};
      launch(ds, 2);
    }
    cls_attn_kernel<<<16, 256, 0, stream>>>(cls_s, Wq_i, bq_i, Wk_i,
                                            bk_i, Wv_i, bv_i,
                                            Kbig, Vt_big, AOc);
    cls_mlp_kernel<<<2, 1024, 0, stream>>>(AOc, cls_s, Wd_i, bd_i, ag_i, ab_i,
                                           W1_i, b1_i, W2_i, b2_i, fg_i, fb_i);
  }

  copyout_kernel<<<5122, 256, 0, stream>>>(qs_s, ks_s, cls_s, (float*)d_out);
}

// Round 15
// 826.770 us; speedup vs baseline: 1.0126x; 1.0059x over previous
//
#include <hip/hip_runtime.h>
#include <math.h>

namespace {
constexpr int kB = 2;
constexpr int kM = 512;
constexpr int kN = 2048;
constexpr int kHID = 256;
constexpr int kDH = 32;
constexpr int kL = 4;
constexpr float kEPS = 1e-5f;
constexpr int kKV = 2560; // Kbig rows / Vt_big cols per batch (2048 ks + 512 qs)
}

typedef __attribute__((ext_vector_type(8))) short short8;
typedef __attribute__((ext_vector_type(4))) float f32x4;

__device__ inline ushort f2b(float f) {
  unsigned u = __builtin_bit_cast(unsigned, f);
  unsigned r = (u + 0x7fffu + ((u >> 16) & 1u)) >> 16;
  return (ushort)r;
}
__device__ inline float b2f(ushort u) {
  return __builtin_bit_cast(float, (unsigned)u << 16);
}
__device__ inline unsigned cvtpk(float lo, float hi) {
  unsigned r;
  asm("v_cvt_pk_bf16_f32 %0, %1, %2" : "=v"(r) : "v"(lo), "v"(hi));
  return r;
}
__device__ inline void gld16(ushort* lds, const ushort* g) {
  __builtin_amdgcn_global_load_lds(
      (const __attribute__((address_space(1))) void*)g,
      (__attribute__((address_space(3))) void*)lds, 16, 0, 0);
}

// dot of 8 bf16 weights with 8 f32 activations from LDS
__device__ inline float dot8(const float* a, short8 w) {
  float s = 0.f;
  #pragma unroll
  for (int jj = 0; jj < 8; ++jj) s += a[jj] * b2f((ushort)w[jj]);
  return s;
}

// ---------------- mask normalization (dtype sniffing) -> additive mask ----------------
__global__ __launch_bounds__(256) void mask_norm_kernel(
    const unsigned char* __restrict__ mraw, float* __restrict__ mf)
{
  int tid = threadIdx.x;
  __shared__ unsigned sh[4];
  if (tid < 4) sh[tid] = 0;
  __syncthreads();
  unsigned l1 = 0, l2 = 0, l3 = 0, l4 = 0;
  for (int j = 0; j < 16; ++j) {
    int p = tid * 16 + j;
    unsigned v = mraw[p];
    int r = p & 3;
    if (r == 1) l1 |= v;
    else if (r == 2) l2 |= v;
    else if (r == 3) l3 |= v;
    else if ((p & 7) == 4) l4 |= v;
  }
  if (l1) atomicOr(&sh[0], l1);
  if (l2) atomicOr(&sh[1], l2);
  if (l3) atomicOr(&sh[2], l3);
  if (l4) atomicOr(&sh[3], l4);
  __syncthreads();
  unsigned a1 = sh[0], a2 = sh[1], a3 = sh[2], a4 = sh[3];
  int mode; // 0=u8, 1=i32, 2=i64, 3=f32
  if ((a1 | a2 | a3) == 0) mode = a4 ? 1 : 2;
  else if (a1 == 0 && (a2 & ~0x80u) == 0 && (a3 & ~0x3Fu) == 0 && ((a2 | a3) != 0))
    mode = 3;
  else mode = 0;

  int i = blockIdx.x * 256 + tid;
  unsigned char v;
  if (mode == 0) v = mraw[i];
  else if (mode == 1) v = mraw[i * 4];
  else if (mode == 2) v = mraw[i * 8];
  else v = mraw[i * 4 + 3];
  mf[i] = v ? 0.f : -2.5505654e9f; // -(1e10 * scale2)
}

// ---------------- unified encoder: sinenc + add + LN1 -> bf16 ----------------
__global__ __launch_bounds__(256) void encode2_kernel(
    const float* __restrict__ qc2, const float* __restrict__ qf2,
    const float* __restrict__ qf3, const float* __restrict__ kc2,
    const float* __restrict__ kf2, const float* __restrict__ kf3,
    const float* __restrict__ g, const float* __restrict__ bb,
    ushort* __restrict__ out)
{
  int row = blockIdx.x; // 0..5119
  const float *c2d, *f2, *f3;
  int r;
  if (row < kB * kM) { c2d = qc2; f2 = qf2; f3 = qf3; r = row; }
  else { c2d = kc2; f2 = kf2; f3 = kf3; r = row - kB * kM; }
  int c = threadIdx.x;
  float coord = c2d[(size_t)r * 2 + (c >> 7)];
  int h = c & 127;
  float ex = (float)(h & ~1) * (1.0f / 128.0f);
  float inv = expf(ex * 9.210340371976184f);
  float val = coord / inv;
  float e = (h & 1) ? cosf(val) : sinf(val);
  float x = f2[(size_t)r * 256 + c] + f3[(size_t)r * 256 + c] + e;
  __shared__ float red[256];
  red[c] = x; __syncthreads();
  for (int s = 128; s > 0; s >>= 1) { if (c < s) red[c] += red[c + s]; __syncthreads(); }
  float mean = red[0] * (1.0f / 256.0f);
  __syncthreads();
  float d = x - mean;
  red[c] = d * d; __syncthreads();
  for (int s = 128; s > 0; s >>= 1) { if (c < s) red[c] += red[c + s]; __syncthreads(); }
  float var = red[0] * (1.0f / 256.0f);
  out[(size_t)row * 256 + c] = f2b(d * rsqrtf(var + kEPS) * g[c] + bb[c]);
}

// ---------------- batched weight convert + transpose ----------------
struct WJobs {
  const float* W[7]; ushort* Wt[7];
  int K[7], C[7], off[7];
};
__global__ __launch_bounds__(256) void wconv_all_kernel(WJobs J)
{
  __shared__ float t[32][33];
  int bid = blockIdx.x;
  int j = 0;
  #pragma unroll
  for (int q = 1; q < 7; ++q) if (bid >= J.off[q]) j = q;
  int tl = bid - J.off[j];
  int K = J.K[j], C = J.C[j];
  int tpl = (K >> 5) * (C >> 5);
  int layer = tl / tpl, rem = tl - layer * tpl;
  int kt = rem % (K >> 5), ct = rem / (K >> 5);
  const float* Wl = J.W[j] + (size_t)layer * K * C;
  ushort* Wtl = J.Wt[j] + (size_t)layer * K * C;
  int k0 = kt * 32, c0 = ct * 32;
  int tx = threadIdx.x & 31, ty = threadIdx.x >> 5;
  for (int i = ty; i < 32; i += 8) t[i][tx] = Wl[(size_t)(k0 + i) * C + c0 + tx];
  __syncthreads();
  for (int i = ty; i < 32; i += 8)
    Wtl[(size_t)(c0 + i) * K + k0 + tx] = f2b(t[tx][i]);
}

// ---------------- batched bf16 MFMA GEMM (64x64 tiles) ----------------
struct GDesc {
  const ushort* A; const ushort* Bt; const float* bias; const float* res; void* out;
  int R, K, C, flags;          // flags: 1 relu, 2 bf16-out, 4 transposed-Vt-out
  int in_rpb, out_rpb, out_off, vt_stride;
};
struct GBatch { GDesc d[5]; };

__global__ __launch_bounds__(256) void gemmx_kernel(GBatch bt)
{
  GDesc d = bt.d[blockIdx.z];
  int r0 = blockIdx.x * 64;
  if (r0 >= d.R) return;
  int c0 = blockIdx.y * 64;

  __shared__ ushort As[4096];
  __shared__ ushort Bs[4096];
  int tid = threadIdx.x;
  int lam = tid & 63, wv = tid >> 6;
  int wr = wv >> 1, wc = wv & 1;
  int K = d.K;
  int srow8 = lam >> 3;
  int sxor = (lam & 7) ^ srow8;

  f32x4 acc[2][2] = {};

  for (int k0 = 0; k0 < K; k0 += 64) {
    #pragma unroll
    for (int i = 0; i < 2; ++i) {
      int row = 16 * wv + 8 * i + srow8;
      gld16(As + wv * 1024 + i * 512,
            d.A + (size_t)(r0 + row) * K + k0 + 8 * sxor);
      gld16(Bs + wv * 1024 + i * 512,
            d.Bt + (size_t)(c0 + row) * K + k0 + 8 * sxor);
    }
    __syncthreads();
    #pragma unroll
    for (int ks = 0; ks < 2; ++ks) {
      short8 af[2], bf_[2];
      #pragma unroll
      for (int m = 0; m < 2; ++m) {
        int ra = wr * 32 + m * 16 + (lam & 15);
        int ch = (ks * 4 + (lam >> 4)) ^ (ra & 7);
        af[m] = *(const short8*)(As + ra * 64 + ch * 8);
      }
      #pragma unroll
      for (int n = 0; n < 2; ++n) {
        int rb = wc * 32 + n * 16 + (lam & 15);
        int ch = (ks * 4 + (lam >> 4)) ^ (rb & 7);
        bf_[n] = *(const short8*)(Bs + rb * 64 + ch * 8);
      }
      #pragma unroll
      for (int m = 0; m < 2; ++m)
        #pragma unroll
        for (int n = 0; n < 2; ++n)
          acc[m][n] = __builtin_amdgcn_mfma_f32_16x16x32_bf16(
              af[m], bf_[n], acc[m][n], 0, 0, 0);
    }
    __syncthreads();
  }

  if (!(d.flags & 4)) {
    #pragma unroll
    for (int m = 0; m < 2; ++m) {
      #pragma unroll
      for (int reg = 0; reg < 4; ++reg) {
        int gr = r0 + wr * 32 + m * 16 + (lam >> 4) * 4 + reg;
        int bidx = gr / d.in_rpb, rr = gr - bidx * d.in_rpb;
        size_t orow = (size_t)bidx * d.out_rpb + d.out_off + rr;
        #pragma unroll
        for (int n = 0; n < 2; ++n) {
          int gc = c0 + wc * 32 + n * 16 + (lam & 15);
          float v = acc[m][n][reg] + d.bias[gc];
          if (d.res) v += d.res[(size_t)gr * d.C + gc];
          if (d.flags & 1) v = fmaxf(v, 0.f);
          if (d.flags & 2) ((ushort*)d.out)[orow * d.C + gc] = f2b(v);
          else ((float*)d.out)[orow * d.C + gc] = v;
        }
      }
    }
  } else {
    #pragma unroll
    for (int m = 0; m < 2; ++m)
      #pragma unroll
      for (int n = 0; n < 2; ++n)
        #pragma unroll
        for (int reg = 0; reg < 4; ++reg) {
          int col = wc * 32 + n * 16 + (lam & 15);
          int row = wr * 32 + m * 16 + (lam >> 4) * 4 + reg;
          float v = acc[m][n][reg] + d.bias[c0 + col];
          As[col * 64 + (((row >> 3) ^ (col & 7)) << 3) + (row & 7)] = f2b(v);
        }
    __syncthreads();
    int col2 = tid >> 2, rc = tid & 3;
    #pragma unroll
    for (int u = 0; u < 2; ++u) {
      int rowc = rc * 2 + u;
      short8 val = *(const short8*)(As + col2 * 64 + ((rowc ^ (col2 & 7)) << 3));
      int r = r0 + rowc * 8;
      int bidx = r / d.in_rpb, rr = r - bidx * d.in_rpb;
      *(short8*)((ushort*)d.out +
                 ((size_t)bidx * 256 + c0 + col2) * d.vt_stride + d.out_off + rr) = val;
    }
  }
}

// ---------------- fused GEMM + bias (+res) + LayerNorm: 16-row x 256-col blocks ----------------
__global__ __launch_bounds__(256) void gemmln_kernel(
    const ushort* __restrict__ A, const ushort* __restrict__ Bt,
    const float* __restrict__ bias, const float* __restrict__ res,
    const float* __restrict__ g, const float* __restrict__ bb,
    float* __restrict__ outf, ushort* __restrict__ outb, int R, int K)
{
  __shared__ ushort As[16 * 64];
  __shared__ ushort Bs[256 * 64];
  __shared__ float redL[16][4];
  int r0 = blockIdx.x * 16;
  int tid = threadIdx.x;
  int lam = tid & 63, wv = tid >> 6;
  int srow8 = lam >> 3;
  int sxor = (lam & 7) ^ srow8;

  f32x4 acc[4] = {};

  for (int k0 = 0; k0 < K; k0 += 64) {
    if (wv < 2)
      gld16(As + wv * 512, A + (size_t)(r0 + wv * 8 + srow8) * K + k0 + 8 * sxor);
    #pragma unroll
    for (int j = 0; j < 8; ++j) {
      int cc = wv * 8 + j;
      gld16(Bs + cc * 512, Bt + (size_t)(cc * 8 + srow8) * K + k0 + 8 * sxor);
    }
    __syncthreads();
    #pragma unroll
    for (int ks = 0; ks < 2; ++ks) {
      int ra = lam & 15;
      int cha = (ks * 4 + (lam >> 4)) ^ (ra & 7);
      short8 af = *(const short8*)(As + ra * 64 + cha * 8);
      #pragma unroll
      for (int cg = 0; cg < 4; ++cg) {
        int rb = wv * 64 + cg * 16 + (lam & 15);
        int chb = (ks * 4 + (lam >> 4)) ^ (rb & 7);
        short8 bf_ = *(const short8*)(Bs + rb * 64 + chb * 8);
        acc[cg] = __builtin_amdgcn_mfma_f32_16x16x32_bf16(af, bf_, acc[cg], 0, 0, 0);
      }
    }
    __syncthreads();
  }

  int col_lo = lam & 15, rsel = lam >> 4;
  float v[4][4];
  #pragma unroll
  for (int cg = 0; cg < 4; ++cg) {
    int col = wv * 64 + cg * 16 + col_lo;
    float bi = bias[col];
    #pragma unroll
    for (int reg = 0; reg < 4; ++reg) {
      int row = r0 + rsel * 4 + reg;
      float x = acc[cg][reg] + bi;
      if (res) x += res[(size_t)row * 256 + col];
      v[cg][reg] = x;
    }
  }
  float mean[4];
  {
    float ps[4];
    #pragma unroll
    for (int reg = 0; reg < 4; ++reg) {
      ps[reg] = v[0][reg] + v[1][reg] + v[2][reg] + v[3][reg];
      #pragma unroll
      for (int o = 1; o < 16; o <<= 1) ps[reg] += __shfl_xor(ps[reg], o);
    }
    if (col_lo == 0)
      #pragma unroll
      for (int reg = 0; reg < 4; ++reg) redL[rsel * 4 + reg][wv] = ps[reg];
    __syncthreads();
    #pragma unroll
    for (int reg = 0; reg < 4; ++reg) {
      int rr = rsel * 4 + reg;
      mean[reg] = (redL[rr][0] + redL[rr][1] + redL[rr][2] + redL[rr][3]) * (1.0f / 256.0f);
    }
    __syncthreads();
  }
  float rs_[4];
  {
    float ps[4];
    #pragma unroll
    for (int reg = 0; reg < 4; ++reg) {
      float s = 0.f;
      #pragma unroll
      for (int cg = 0; cg < 4; ++cg) {
        float dd = v[cg][reg] - mean[reg];
        s += dd * dd;
      }
      ps[reg] = s;
      #pragma unroll
      for (int o = 1; o < 16; o <<= 1) ps[reg] += __shfl_xor(ps[reg], o);
    }
    if (col_lo == 0)
      #pragma unroll
      for (int reg = 0; reg < 4; ++reg) redL[rsel * 4 + reg][wv] = ps[reg];
    __syncthreads();
    #pragma unroll
    for (int reg = 0; reg < 4; ++reg) {
      int rr = rsel * 4 + reg;
      float var = (redL[rr][0] + redL[rr][1] + redL[rr][2] + redL[rr][3]) * (1.0f / 256.0f);
      rs_[reg] = rsqrtf(var + kEPS);
    }
  }
  #pragma unroll
  for (int cg = 0; cg < 4; ++cg) {
    int col = wv * 64 + cg * 16 + col_lo;
    float gg = g[col], bv = bb[col];
    #pragma unroll
    for (int reg = 0; reg < 4; ++reg) {
      int row = r0 + rsel * 4 + reg;
      float y = (v[cg][reg] - mean[reg]) * rs_[reg] * gg + bv;
      outf[(size_t)row * 256 + col] = y;
      outb[(size_t)row * 256 + col] = f2b(y);
    }
  }
}

// ---------------- MFMA flash attention v7: 128-key LDS stages (half the barriers) ----------------
__global__ __launch_bounds__(256) void attn6_kernel(
    const ushort* __restrict__ Qp, const ushort* __restrict__ Kp,
    const ushort* __restrict__ Vt, float* __restrict__ Pp,
    const float* __restrict__ madd,
    int Sq, int k_rpb, int vt_stride, int self_off, int slen, int ns)
{
  __shared__ ushort KsL[2 * 64 * 32];  // two 64-key sub-tiles: [key][chunk^((key>>1)&3)]
  __shared__ ushort VtL[2 * 32 * 64];  // two sub-tiles: [d][chunk^(d&7)]
  int bh = blockIdx.x;
  int b = bh >> 3, h = bh & 7;
  int sidx = blockIdx.z;
  int tid = threadIdx.x;
  int lane = tid & 63;
  int qlane = lane & 15, g = lane >> 4;
  int gq = blockIdx.y * 64 + (tid >> 6) * 16 + qlane;
  const float scale2 = 0.17677669529663688f * 1.4426950408889634f;

  short8 qB = *(const short8*)(Qp + ((size_t)(b * Sq + gq)) * 256 + h * 32 + g * 8);

  float mi = -3.0e38f, li = 0.f;
  f32x4 acc0 = {}, acc1 = {};

  if (self_off >= 0 && sidx == 0) {
    const ushort* kr = Kp + ((size_t)(b * k_rpb + self_off + gq)) * 256 + h * 32 + g * 8;
    short8 k8 = *(const short8*)kr;
    float part = 0.f;
    #pragma unroll
    for (int j = 0; j < 8; ++j) part += b2f((ushort)qB[j]) * b2f((ushort)k8[j]);
    part += __shfl_xor(part, 16);
    part += __shfl_xor(part, 32);
    mi = part * scale2;
    li = 1.f;
    const ushort* vb = Vt + ((size_t)(b * 256 + h * 32)) * vt_stride + self_off + gq;
    #pragma unroll
    for (int r = 0; r < 4; ++r) {
      acc0[r] = b2f(vb[(size_t)(4 * g + r) * vt_stride]);
      acc1[r] = b2f(vb[(size_t)(16 + 4 * g + r) * vt_stride]);
    }
  }

  const float* mb = madd + (size_t)b * kN;
  int skey = tid >> 2, sc = tid & 3;   // K staging: key row, 8-elem chunk
  int sd = tid >> 3, sc8 = tid & 7;    // V^T staging: d row, 8-key chunk
  const ushort* Ksrc = Kp + ((size_t)(b * k_rpb + skey)) * 256 + h * 32 + sc * 8;
  const ushort* Vsrc = Vt + ((size_t)(b * 256 + h * 32 + sd)) * vt_stride + sc8 * 8;
  ushort* Kdst = KsL + skey * 32 + ((sc ^ ((skey >> 1) & 3)) << 3);
  ushort* Vdst = VtL + sd * 64 + ((sc8 ^ (sd & 7)) << 3);

  int base = sidx * slen;
  int ntile = slen >> 7;  // 128-key stages

  for (int it = 0; it < ntile; ++it) {
    int n0 = base + it * 128;
    __syncthreads();  // prev stage's LDS reads complete
    #pragma unroll
    for (int s = 0; s < 2; ++s) {
      *(short8*)(Kdst + s * 2048) = *(const short8*)(Ksrc + (size_t)(n0 + s * 64) * 256);
      *(short8*)(Vdst + s * 2048) = *(const short8*)(Vsrc + n0 + s * 64);
    }
    __syncthreads();

    #pragma unroll
    for (int s = 0; s < 2; ++s) {
      const ushort* KsB = KsL + s * 2048;
      const ushort* VtB = VtL + s * 2048;
      int nb = n0 + s * 64;

      float4 m4[4];
      #pragma unroll
      for (int f = 0; f < 4; ++f)
        m4[f] = *(const float4*)(mb + nb + 16 * f + 4 * g);

      f32x4 st[4];
      __builtin_amdgcn_s_setprio(1);
      #pragma unroll
      for (int f = 0; f < 4; ++f) {
        int key = f * 16 + qlane;
        short8 kf = *(const short8*)(KsB + key * 32 + ((g ^ ((key >> 1) & 3)) << 3));
        st[f] = __builtin_amdgcn_mfma_f32_16x16x32_bf16(
            kf, qB, (f32x4){0.f, 0.f, 0.f, 0.f}, 0, 0, 0);
      }
      __builtin_amdgcn_s_setprio(0);

      float p[4][4];
      float tm = -3.0e38f;
      #pragma unroll
      for (int f = 0; f < 4; ++f) {
        float mm[4] = {m4[f].x, m4[f].y, m4[f].z, m4[f].w};
        #pragma unroll
        for (int r = 0; r < 4; ++r) {
          float sv = fmaf(st[f][r], scale2, mm[r]);
          p[f][r] = sv;
          tm = fmaxf(tm, sv);
        }
      }
      tm = fmaxf(tm, __shfl_xor(tm, 16));
      tm = fmaxf(tm, __shfl_xor(tm, 32));
      if (__any(tm > mi + 11.5f)) {  // defer-max
        float nm = fmaxf(mi, tm);
        float fs = exp2f(mi - nm);
        li *= fs; mi = nm;
        #pragma unroll
        for (int r = 0; r < 4; ++r) { acc0[r] *= fs; acc1[r] *= fs; }
      }
      float ls = 0.f;
      #pragma unroll
      for (int f = 0; f < 4; ++f)
        #pragma unroll
        for (int r = 0; r < 4; ++r) {
          float pv = exp2f(p[f][r] - mi);
          p[f][r] = pv;
          ls += pv;
        }
      ls += __shfl_xor(ls, 16);
      ls += __shfl_xor(ls, 32);
      li += ls;

      // P^T -> bf16 B-fragments via pack + 8 shfl per 32-key half
      unsigned pkw[4][2];
      #pragma unroll
      for (int f = 0; f < 4; ++f) {
        pkw[f][0] = cvtpk(p[f][0], p[f][1]);
        pkw[f][1] = cvtpk(p[f][2], p[f][3]);
      }
      int src0 = qlane | ((2 * (g & 1)) << 4);
      int src1 = src0 + 16;
      bool hi = g >= 2;
      #pragma unroll
      for (int t = 0; t < 2; ++t) {
        unsigned t0 = (unsigned)__shfl((int)pkw[2 * t][0], src0);
        unsigned t1 = (unsigned)__shfl((int)pkw[2 * t][1], src0);
        unsigned t2 = (unsigned)__shfl((int)pkw[2 * t][0], src1);
        unsigned t3 = (unsigned)__shfl((int)pkw[2 * t][1], src1);
        unsigned u0 = (unsigned)__shfl((int)pkw[2 * t + 1][0], src0);
        unsigned u1 = (unsigned)__shfl((int)pkw[2 * t + 1][1], src0);
        unsigned u2 = (unsigned)__shfl((int)pkw[2 * t + 1][0], src1);
        unsigned u3 = (unsigned)__shfl((int)pkw[2 * t + 1][1], src1);
        union { unsigned u[4]; short8 v; } pb;
        pb.u[0] = hi ? u0 : t0;
        pb.u[1] = hi ? u1 : t1;
        pb.u[2] = hi ? u2 : t2;
        pb.u[3] = hi ? u3 : t3;
        __builtin_amdgcn_s_setprio(1);
        int d0 = qlane, d1 = 16 + qlane;
        short8 vf0 = *(const short8*)(VtB + d0 * 64 + (((t * 4 + g) ^ (d0 & 7)) << 3));
        acc0 = __builtin_amdgcn_mfma_f32_16x16x32_bf16(vf0, pb.v, acc0, 0, 0, 0);
        short8 vf1 = *(const short8*)(VtB + d1 * 64 + (((t * 4 + g) ^ (d1 & 7)) << 3));
        acc1 = __builtin_amdgcn_mfma_f32_16x16x32_bf16(vf1, pb.v, acc1, 0, 0, 0);
        __builtin_amdgcn_s_setprio(0);
      }
    }
  }

  float* rec = Pp + ((size_t)(bh * Sq + gq) * ns + sidx) * 20;
  if (g == 0) { rec[0] = mi; rec[1] = li; }
  ushort* accp = (ushort*)(rec + 2);
  uint2 w0, w1;
  w0.x = cvtpk(acc0[0], acc0[1]); w0.y = cvtpk(acc0[2], acc0[3]);
  w1.x = cvtpk(acc1[0], acc1[1]); w1.y = cvtpk(acc1[2], acc1[3]);
  *(uint2*)(accp + 4 * g) = w0;
  *(uint2*)(accp + 16 + 4 * g) = w1;
}

// ---------------- split-K combine: merge ns partials, write bf16 AO ----------------
__global__ __launch_bounds__(256) void combine_kernel(
    const float* __restrict__ Pp, ushort* __restrict__ AO, int Sq, int ns)
{
  int r = blockIdx.x * 8 + (threadIdx.x >> 5);
  int d = threadIdx.x & 31;
  int bh = r / Sq, q = r - bh * Sq;
  int b = bh >> 3, h = bh & 7;
  const float* rb = Pp + (size_t)r * ns * 20;
  float M = -3.0e38f;
  for (int s2 = 0; s2 < ns; ++s2) M = fmaxf(M, rb[s2 * 20]);
  float L = 0.f, O = 0.f;
  for (int s2 = 0; s2 < ns; ++s2) {
    float w = exp2f(rb[s2 * 20] - M);
    L += rb[s2 * 20 + 1] * w;
    O += w * b2f(((const ushort*)(rb + s2 * 20 + 2))[d]);
  }
  AO[((size_t)(b * Sq + q)) * 256 + h * 32 + d] = f2b(O / L);
}

// ---------------- fused cls attention (one block per (b,h)) ----------------
__global__ __launch_bounds__(256) void cls_attn_kernel(
    const float* __restrict__ cls_s,
    const ushort* __restrict__ WqT, const float* __restrict__ bq,
    const ushort* __restrict__ WkT, const float* __restrict__ bk,
    const ushort* __restrict__ WvT, const float* __restrict__ bv,
    const ushort* __restrict__ Kbig, const ushort* __restrict__ Vt,
    float* __restrict__ AOc)
{
  __shared__ float c0f[256], qv[32], k0v[32], v0v[32];
  __shared__ float red[256];
  __shared__ float sarr[2560];
  __shared__ float scl[4];
  const float scale2 = 0.17677669529663688f * 1.4426950408889634f;
  int b = blockIdx.x >> 3, h = blockIdx.x & 7;
  int t = threadIdx.x;
  c0f[t] = cls_s[b * 256 + t];
  __syncthreads();

  const ushort* Wm[3] = {WqT, WkT, WvT};
  const float* Bi[3] = {bq, bk, bv};
  float* Ov[3] = {qv, k0v, v0v};
  for (int pi = 0; pi < 3; ++pi) {
    int d = t >> 3, sl = t & 7;
    const ushort* wrow = Wm[pi] + (size_t)(h * 32 + d) * 256 + sl * 32;
    float part = 0.f;
    #pragma unroll
    for (int j = 0; j < 32; j += 8) {
      short8 w8 = *(const short8*)(wrow + j);
      #pragma unroll
      for (int jj = 0; jj < 8; ++jj) part += c0f[sl * 32 + j + jj] * b2f((ushort)w8[jj]);
    }
    red[t] = part;
    __syncthreads();
    if (t < 32) {
      float sum = 0.f;
      #pragma unroll
      for (int s = 0; s < 8; ++s) sum += red[t * 8 + s];
      Ov[pi][t] = sum + Bi[pi][h * 32 + t];
    }
    __syncthreads();
  }

  if (t < 32) red[t] = qv[t] * k0v[t];
  __syncthreads();
  if (t == 0) {
    float sc = 0.f;
    for (int j = 0; j < 32; ++j) sc += red[j];
    scl[0] = sc * scale2;
  }
  __syncthreads();

  float lmax = -3.0e38f;
  for (int it = 0; it < 10; ++it) {
    int key = t + it * 256;
    const ushort* krow = Kbig + ((size_t)(b * kKV + key)) * 256 + h * 32;
    float sdot = 0.f;
    #pragma unroll
    for (int j = 0; j < 4; ++j) {
      short8 k8 = ((const short8*)krow)[j];
      #pragma unroll
      for (int jj = 0; jj < 8; ++jj) sdot += qv[j * 8 + jj] * b2f((ushort)k8[jj]);
    }
    sdot *= scale2;
    sarr[key] = sdot;
    lmax = fmaxf(lmax, sdot);
  }
  red[t] = lmax;
  __syncthreads();
  for (int s = 128; s > 0; s >>= 1) { if (t < s) red[t] = fmaxf(red[t], red[t + s]); __syncthreads(); }
  if (t == 0) scl[1] = fmaxf(red[0], scl[0]);
  __syncthreads();
  float M = scl[1];
  float lsum = 0.f;
  for (int it = 0; it < 10; ++it) {
    int key = t + it * 256;
    float pv = exp2f(sarr[key] - M);
    sarr[key] = pv;
    lsum += pv;
  }
  red[t] = lsum;
  __syncthreads();
  for (int s = 128; s > 0; s >>= 1) { if (t < s) red[t] += red[t + s]; __syncthreads(); }
  if (t == 0) {
    scl[3] = exp2f(scl[0] - M);
    scl[2] = red[0] + scl[3];
  }
  __syncthreads();

  {
    int d = t & 31, sl = t >> 5;
    const ushort* vrow = Vt + ((size_t)(b * 256 + h * 32 + d)) * kKV + sl * 320;
    float acc = 0.f;
    for (int j = 0; j < 320; j += 8) {
      short8 v8 = *(const short8*)(vrow + j);
      #pragma unroll
      for (int jj = 0; jj < 8; ++jj) acc += sarr[sl * 320 + j + jj] * b2f((ushort)v8[jj]);
    }
    red[sl * 32 + d] = acc;
  }
  __syncthreads();
  if (t < 32) {
    float o = scl[3] * v0v[t];
    #pragma unroll
    for (int s = 0; s < 8; ++s) o += red[s * 32 + t];
    AOc[b * 256 + h * 32 + t] = o / scl[2];
  }
}

// ---------------- fused cls MLP (1024 threads, 8-lane-per-row coalesced reads) ----------------
__device__ inline float blk_sum1024(float v, float* red, int t) {
  red[t] = v; __syncthreads();
  for (int s = 512; s > 0; s >>= 1) {
    if (t < s) red[t] += red[t + s];
    __syncthreads();
  }
  float r = red[0];
  __syncthreads();
  return r;
}

__global__ __launch_bounds__(1024) void cls_mlp_kernel(
    const float* __restrict__ AOc, float* __restrict__ cls_s,
    const ushort* __restrict__ WdT, const float* __restrict__ bd,
    const float* __restrict__ ag, const float* __restrict__ ab,
    const ushort* __restrict__ W1T, const float* __restrict__ b1,
    const ushort* __restrict__ W2T, const float* __restrict__ b2,
    const float* __restrict__ fg, const float* __restrict__ fb)
{
  __shared__ float oL[256], r0L[256], aL[256], ffL[1024], vL[256], red[1024];
  int b = blockIdx.x, t = threadIdx.x; // 0..1023
  if (t < 256) { oL[t] = AOc[b * 256 + t]; r0L[t] = cls_s[b * 256 + t]; }
  __syncthreads();

  int r8 = t >> 3, c8 = t & 7; // 8 lanes cooperate on one row (coalesced 128B/row)
  // Wd projection (256 rows, K=256): 2 passes of 128 rows
  #pragma unroll
  for (int p = 0; p < 2; ++p) {
    int row = p * 128 + r8;
    const ushort* wr_ = WdT + (size_t)row * 256 + c8 * 8;
    float a0 = 0.f, a1 = 0.f, a2 = 0.f, a3 = 0.f;
    a0 = dot8(oL + c8 * 8, *(const short8*)(wr_));
    a1 = dot8(oL + c8 * 8 + 64, *(const short8*)(wr_ + 64));
    a2 = dot8(oL + c8 * 8 + 128, *(const short8*)(wr_ + 128));
    a3 = dot8(oL + c8 * 8 + 192, *(const short8*)(wr_ + 192));
    float s = (a0 + a1) + (a2 + a3);
    s += __shfl_xor(s, 1);
    s += __shfl_xor(s, 2);
    s += __shfl_xor(s, 4);
    if (c8 == 0) vL[row] = s + bd[row] + r0L[row];
  }
  __syncthreads();
  // LN #1
  {
    float x = (t < 256) ? vL[t] : 0.f;
    float mean = blk_sum1024(x, red, t) * (1.0f / 256.0f);
    float d = (t < 256) ? (vL[t] - mean) : 0.f;
    float var = blk_sum1024(d * d, red, t) * (1.0f / 256.0f);
    float rs = rsqrtf(var + kEPS);
    if (t < 256) aL[t] = d * rs * ag[t] + ab[t];
  }
  __syncthreads();
  // FF1 (1024 rows, K=256) + relu: 8 passes of 128 rows
  #pragma unroll
  for (int p = 0; p < 8; ++p) {
    int row = p * 128 + r8;
    const ushort* w1r = W1T + (size_t)row * 256 + c8 * 8;
    float a0 = dot8(aL + c8 * 8, *(const short8*)(w1r));
    float a1 = dot8(aL + c8 * 8 + 64, *(const short8*)(w1r + 64));
    float a2 = dot8(aL + c8 * 8 + 128, *(const short8*)(w1r + 128));
    float a3 = dot8(aL + c8 * 8 + 192, *(const short8*)(w1r + 192));
    float s = (a0 + a1) + (a2 + a3);
    s += __shfl_xor(s, 1);
    s += __shfl_xor(s, 2);
    s += __shfl_xor(s, 4);
    if (c8 == 0) ffL[row] = fmaxf(s + b1[row], 0.f);
  }
  __syncthreads();
  // FF2 (256 rows, K=1024): 2 passes of 128 rows; 16 chunks per thread
  #pragma unroll
  for (int p = 0; p < 2; ++p) {
    int row = p * 128 + r8;
    const ushort* w2r = W2T + (size_t)row * 1024 + c8 * 8;
    float a0 = 0.f, a1 = 0.f, a2 = 0.f, a3 = 0.f;
    #pragma unroll
    for (int j = 0; j < 1024; j += 256) {
      a0 += dot8(ffL + c8 * 8 + j, *(const short8*)(w2r + j));
      a1 += dot8(ffL + c8 * 8 + j + 64, *(const short8*)(w2r + j + 64));
      a2 += dot8(ffL + c8 * 8 + j + 128, *(const short8*)(w2r + j + 128));
      a3 += dot8(ffL + c8 * 8 + j + 192, *(const short8*)(w2r + j + 192));
    }
    float s = (a0 + a1) + (a2 + a3);
    s += __shfl_xor(s, 1);
    s += __shfl_xor(s, 2);
    s += __shfl_xor(s, 4);
    if (c8 == 0) vL[row] = s + b2[row] + aL[row];
  }
  __syncthreads();
  // LN #2
  {
    float x = (t < 256) ? vL[t] : 0.f;
    float mean = blk_sum1024(x, red, t) * (1.0f / 256.0f);
    float d = (t < 256) ? (vL[t] - mean) : 0.f;
    float var = blk_sum1024(d * d, red, t) * (1.0f / 256.0f);
    float rs = rsqrtf(var + kEPS);
    if (t < 256) cls_s[b * 256 + t] = d * rs * fg[t] + fb[t];
  }
}

__global__ void cls_init_kernel(const float* __restrict__ cf, float* __restrict__ cls)
{
  int i = blockIdx.x * 256 + threadIdx.x;
  cls[i] = cf[i & 255];
}

__global__ __launch_bounds__(256) void copyout_kernel(
    const float* __restrict__ qs, const float* __restrict__ ks,
    const float* __restrict__ cls, float* __restrict__ out)
{
  int i = blockIdx.x * 256 + threadIdx.x;
  float v;
  if (i < 262144) v = qs[i];
  else if (i < 1310720) v = ks[i - 262144];
  else v = cls[i - 1310720];
  out[i] = v;
}

extern "C" void kernel_launch(void* const* d_in, const int* in_sizes, int n_in,
                              void* d_out, int out_size, void* d_ws, size_t ws_size,
                              hipStream_t stream)
{
  const float* qc2    = (const float*)d_in[0];
  const float* qf2    = (const float*)d_in[1];
  const float* qf3    = (const float*)d_in[2];
  const float* kc2    = (const float*)d_in[3];
  const float* kf2    = (const float*)d_in[4];
  const float* kf3    = (const float*)d_in[5];
  const unsigned char* mraw = (const unsigned char*)d_in[6];
  const float* ln1_g  = (const float*)d_in[7];
  const float* ln1_b  = (const float*)d_in[8];
  const float* dc_W   = (const float*)d_in[9];
  const float* dc_b   = (const float*)d_in[10];
  const float* dcln_g = (const float*)d_in[11];
  const float* dcln_b = (const float*)d_in[12];
  const float* cls_f  = (const float*)d_in[13];
  const float* Wq     = (const float*)d_in[14];
  const float* bq     = (const float*)d_in[15];
  const float* Wk     = (const float*)d_in[16];
  const float* bk     = (const float*)d_in[17];
  const float* Wv     = (const float*)d_in[18];
  const float* bv     = (const float*)d_in[19];
  const float* Wd     = (const float*)d_in[20];
  const float* bd     = (const float*)d_in[21];
  const float* aln_g  = (const float*)d_in[22];
  const float* aln_b  = (const float*)d_in[23];
  const float* W1     = (const float*)d_in[24];
  const float* b1     = (const float*)d_in[25];
  const float* W2     = (const float*)d_in[26];
  const float* b2     = (const float*)d_in[27];
  const float* fln_g  = (const float*)d_in[28];
  const float* fln_b  = (const float*)d_in[29];

  float* ws = (float*)d_ws;
  float* maskf = ws + 0;          // 4096 (additive)
  float* qs_s  = ws + 4096;       // 262144   (qs_s and ks_s adjacent!)
  float* ks_s  = ws + 266240;     // 1048576
  float* cls_s = ws + 1314816;    // 512
  float* AOc   = ws + 1315328;    // 512
  float* Scr   = ws + 1316864;
  float* Ta    = Scr;                 // 1048576 ('a' f32)
  float* ksPart = Scr + 1048576;      // ns=4: 16*2048*4*20 = 2621440 (fits exactly)
  float* qsPart = Scr + 1048576;      // ns=4: 16*512*4*20 = 655360 (reuses region)
  ushort* ub   = (ushort*)(ws + 4986880);
  ushort* qs_b   = ub + 0;            // 262144  (qs_b and ks_b adjacent!)
  ushort* ks_b   = ub + 262144;       // 1048576
  ushort* T2b    = ub + 1310720;      // 1048576 ('a' bf16)
  ushort* Kbig   = ub + 2359296;      // 1310720 (B x 2560 x 256)
  ushort* Vt_ks  = ub + 3670016;      // 1048576 (B x 256 x 2048)
  ushort* Vt_big = ub + 4718592;      // 1310720 (B x 256 x 2560)
  ushort* FFb    = ub + 6029312;      // 4194304 (overlays encT|Qb|Kks|AOb)
  ushort* encT   = FFb + 0;           // 1310720 (5120 x 256)
  ushort* Qb     = FFb + 0;           // 1048576
  ushort* Kks    = FFb + 1048576;     // 1048576
  ushort* AOb    = FFb + 2097152;     // 1048576
  ushort* wts    = ub + 10223616;
  ushort* dcWt = wts;
  ushort* WqT  = wts + 65536;
  ushort* WkT  = WqT + 262144;
  ushort* WvT  = WkT + 262144;
  ushort* WdT  = WvT + 262144;
  ushort* W1T  = WdT + 262144;
  ushort* W2T  = W1T + 1048576;
  // total ~44.7 MB

  auto mk = [](const ushort* A, const ushort* Bt, const float* bias, const float* res,
               void* out, int R, int K, int C, int flags,
               int in_rpb, int out_rpb, int out_off, int vt_stride) {
    GDesc g; g.A = A; g.Bt = Bt; g.bias = bias; g.res = res; g.out = out;
    g.R = R; g.K = K; g.C = C; g.flags = flags; g.in_rpb = in_rpb;
    g.out_rpb = out_rpb; g.out_off = out_off; g.vt_stride = vt_stride; return g;
  };
  auto launch = [&](const GDesc* ds, int n) {
    GBatch bt{};
    int maxR = 0;
    for (int i = 0; i < n; ++i) { bt.d[i] = ds[i]; if (ds[i].R > maxR) maxR = ds[i].R; }
    gemmx_kernel<<<dim3(maxR / 64, ds[0].C / 64, n), 256, 0, stream>>>(bt);
  };
  auto gln = [&](const ushort* A, const ushort* Bt, const float* bias, const float* res,
                 const float* g_, const float* b_, float* of, ushort* ob, int R, int K) {
    gemmln_kernel<<<R / 16, 256, 0, stream>>>(A, Bt, bias, res, g_, b_, of, ob, R, K);
  };

  mask_norm_kernel<<<16, 256, 0, stream>>>(mraw, maskf);

  // weight convert (batched)
  {
    WJobs J;
    const float* Ws[7] = {dc_W, Wq, Wk, Wv, Wd, W1, W2};
    ushort* Ts[7] = {dcWt, WqT, WkT, WvT, WdT, W1T, W2T};
    int Ks[7] = {256, 256, 256, 256, 256, 256, 1024};
    int Cs[7] = {256, 256, 256, 256, 256, 1024, 256};
    int Ls[7] = {1, 4, 4, 4, 4, 4, 4};
    int off = 0;
    for (int j = 0; j < 7; ++j) {
      J.W[j] = Ws[j]; J.Wt[j] = Ts[j]; J.K[j] = Ks[j]; J.C[j] = Cs[j]; J.off[j] = off;
      off += (Ks[j] / 32) * (Cs[j] / 32) * Ls[j];
    }
    wconv_all_kernel<<<off, 256, 0, stream>>>(J);
  }

  // encoders (single gln over 5120 rows: qs rows then ks rows, adjacent outputs)
  encode2_kernel<<<kB * (kM + kN), 256, 0, stream>>>(qc2, qf2, qf3, kc2, kf2, kf3,
                                                     ln1_g, ln1_b, encT);
  gln(encT, dcWt, dc_b, nullptr, dcln_g, dcln_b, qs_s, qs_b, kB * (kM + kN), 256);
  cls_init_kernel<<<2, 256, 0, stream>>>(cls_f, cls_s);

  for (int i = 0; i < kL; ++i) {
    const ushort* Wq_i = WqT + (size_t)i * 65536;  const float* bq_i = bq + i * 256;
    const ushort* Wk_i = WkT + (size_t)i * 65536;  const float* bk_i = bk + i * 256;
    const ushort* Wv_i = WvT + (size_t)i * 65536;  const float* bv_i = bv + i * 256;
    const ushort* Wd_i = WdT + (size_t)i * 65536;  const float* bd_i = bd + i * 256;
    const float* ag_i = aln_g + i * 256;           const float* ab_i = aln_b + i * 256;
    const ushort* W1_i = W1T + (size_t)i * 262144; const float* b1_i = b1 + i * 1024;
    const ushort* W2_i = W2T + (size_t)i * 262144; const float* b2_i = b2 + i * 256;
    const float* fg_i = fln_g + i * 256;           const float* fb_i = fln_b + i * 256;
    int Rk = kB * kN, Rq = kB * kM;

    // ---- ks sublayer ----
    {
      GDesc ds[3] = {
        mk(ks_b, Wq_i, bq_i, nullptr, Qb,  Rk, 256, 256, 2, Rk, Rk, 0, 0),
        mk(ks_b, Wk_i, bk_i, nullptr, Kks, Rk, 256, 256, 2, Rk, Rk, 0, 0),
        mk(ks_b, Wv_i, bv_i, nullptr, Vt_ks, Rk, 256, 256, 4, kN, 0, 0, kN)};
      launch(ds, 3);
    }
    attn6_kernel<<<dim3(kB * 8, kN / 64, 4), 256, 0, stream>>>(
        Qb, Kks, Vt_ks, ksPart, maskf, kN, kN, kN, -1, kN / 4, 4);
    combine_kernel<<<kB * 8 * kN / 8, 256, 0, stream>>>(ksPart, AOb, kN, 4);
    gln(AOb, Wd_i, bd_i, ks_s, ag_i, ab_i, Ta, T2b, Rk, 256);
    { GDesc d = mk(T2b, W1_i, b1_i, nullptr, FFb, Rk, 256, 1024, 1 | 2, Rk, Rk, 0, 0);
      launch(&d, 1); }
    gln(FFb, W2_i, b2_i, Ta, fg_i, fb_i, ks_s, ks_b, Rk, 1024);

    // ---- qs sublayer (query_self, keys = new ks) ----
    {
      GDesc ds[5] = {
        mk(qs_b, Wq_i, bq_i, nullptr, Qb, Rq, 256, 256, 2, Rq, Rq, 0, 0),
        mk(ks_b, Wk_i, bk_i, nullptr, Kbig, Rk, 256, 256, 2, kN, kKV, 0, 0),
        mk(ks_b, Wv_i, bv_i, nullptr, Vt_big, Rk, 256, 256, 4, kN, 0, 0, kKV),
        mk(qs_b, Wk_i, bk_i, nullptr, Kbig, Rq, 256, 256, 2, kM, kKV, kN, 0),
        mk(qs_b, Wv_i, bv_i, nullptr, Vt_big, Rq, 256, 256, 4, kM, 0, kN, kKV)};
      launch(ds, 5);
    }
    attn6_kernel<<<dim3(kB * 8, kM / 64, 4), 256, 0, stream>>>(
        Qb, Kbig, Vt_big, qsPart, maskf, kM, kKV, kKV, kN, kN / 4, 4);
    combine_kernel<<<kB * 8 * kM / 8, 256, 0, stream>>>(qsPart, AOb, kM, 4);
    gln(AOb, Wd_i, bd_i, qs_s, ag_i, ab_i, Ta, T2b, Rq, 256);
    { GDesc d = mk(T2b, W1_i, b1_i, nullptr, FFb, Rq, 256, 1024, 1 | 2, Rq, Rq, 0, 0);
      launch(&d, 1); }
    gln(FFb, W2_i, b2_i, Ta, fg_i, fb_i, qs_s, qs_b, Rq, 1024);

    // ---- cls sublayer ----
    {
      GDesc ds[2] = {
        mk(qs_b, Wk_i, bk_i, nullptr, Kbig, Rq, 256, 256, 2, kM, kKV, kN, 0),
        mk(qs_b, Wv_i, bv_i, nullptr, Vt_big, Rq, 256, 256, 4, kM, 0, kN, kKV)};
      launch(ds, 2);
    }
    cls_attn_kernel<<<16, 256, 0, stream>>>(cls_s, Wq_i, bq_i, Wk_i,
                                            bk_i, Wv_i, bv_i,
                                            Kbig, Vt_big, AOc);
    cls_mlp_kernel<<<2, 1024, 0, stream>>>(AOc, cls_s, Wd_i, bd_i, ag_i, ab_i,
                                           W1_i, b1_i, W2_i, b2_i, fg_i, fb_i);
  }

  copyout_kernel<<<5122, 256, 0, stream>>>(qs_s, ks_s, cls_s, (float*)d_out);
}